// Round 1
// baseline (1008.567 us; speedup 1.0000x reference)
//
#include <hip/hip_runtime.h>
#include <hip/hip_bf16.h>
#include <math.h>

// ---------------- problem constants ----------------
#define H      1280          // hidden == intermediate
#define NE     16            // total experts (2 shared + 14 routed)
#define NR     14            // routed experts
#define TK     4             // top-k routed per token
#define T      4096          // tokens (B*S = 2*2048)
#define NROWS  24576         // 2*T shared rows + 4*T routed pair rows

typedef __bf16 bf16x8 __attribute__((ext_vector_type(8)));
typedef float  f32x4  __attribute__((ext_vector_type(4)));

__device__ __forceinline__ unsigned short f2bf(float f) {
  // round-to-nearest-even fp32 -> bf16 (finite inputs only)
  unsigned int u = __float_as_uint(f);
  u += 0x7fffu + ((u >> 16) & 1u);
  return (unsigned short)(u >> 16);
}

// ---------------- small setup kernels ----------------
__global__ void k_init(int* cnt, int* fill) {
  int i = threadIdx.x;
  if (i < 16) { cnt[i] = 0; fill[i] = 0; }
}

// xb = bf16(x); out = x (residual init)
__global__ void k_cast_x(const float* __restrict__ x,
                         unsigned short* __restrict__ xb,
                         float* __restrict__ out) {
  int i = blockIdx.x * 256 + threadIdx.x;     // T*H/4 threads
  float4 v = reinterpret_cast<const float4*>(x)[i];
  reinterpret_cast<float4*>(out)[i] = v;
  ushort4 b;
  b.x = f2bf(v.x); b.y = f2bf(v.y); b.z = f2bf(v.z); b.w = f2bf(v.w);
  reinterpret_cast<ushort4*>(xb)[i] = b;
}

// Transpose+convert all 32 weight matrices (16x W1, 16x W2), 1280x1280 each.
// dst[n][k] = src[k][n] in bf16 so GEMM B-tiles are K-contiguous rows.
__global__ void k_transpose(const float* __restrict__ W1s, const float* __restrict__ W2s,
                            const float* __restrict__ W1r, const float* __restrict__ W2r,
                            unsigned short* __restrict__ w1b, unsigned short* __restrict__ w2b) {
  int mat = blockIdx.z;
  int fam = mat >> 4;       // 0 -> W1 family, 1 -> W2 family
  int e   = mat & 15;       // expert slot: 0,1 shared; 2..15 routed
  size_t msz = (size_t)H * H;
  const float* src;
  unsigned short* dst;
  if (fam == 0) {
    src = (e < 2) ? W1s + (size_t)e * msz : W1r + (size_t)(e - 2) * msz;
    dst = w1b + (size_t)e * msz;
  } else {
    src = (e < 2) ? W2s + (size_t)e * msz : W2r + (size_t)(e - 2) * msz;
    dst = w2b + (size_t)e * msz;
  }
  __shared__ float tile[32][33];              // +1 pad: conflict-free transpose
  int tx = threadIdx.x & 31;
  int ty = threadIdx.x >> 5;                  // 0..7
  int bx = blockIdx.x * 32;                   // src col base
  int by = blockIdx.y * 32;                   // src row base
#pragma unroll
  for (int rr = 0; rr < 32; rr += 8)
    tile[ty + rr][tx] = src[(size_t)(by + ty + rr) * H + bx + tx];
  __syncthreads();
#pragma unroll
  for (int rr = 0; rr < 32; rr += 8)
    dst[(size_t)(bx + ty + rr) * H + by + tx] = f2bf(tile[tx][ty + rr]);
}

// ---------------- router: logits -> softmax -> top4 ----------------
// one wave per token
__global__ void k_router(const float* __restrict__ x, const float* __restrict__ Wr,
                         const float* __restrict__ br,
                         int* __restrict__ topk_e, float* __restrict__ topk_g,
                         int* __restrict__ cnt) {
  int t  = blockIdx.x;
  int ln = threadIdx.x;                        // 0..63
  float part[NR];
#pragma unroll
  for (int e = 0; e < NR; e++) part[e] = 0.f;
  const float* xr = x + (size_t)t * H;
  for (int k = ln; k < H; k += 64) {
    float xv = xr[k];
    const float* w = Wr + (size_t)k * NR;
#pragma unroll
    for (int e = 0; e < NR; e++) part[e] += xv * w[e];
  }
  float aff[NR];
#pragma unroll
  for (int e = 0; e < NR; e++) {
    float v = part[e];
#pragma unroll
    for (int off = 32; off; off >>= 1) v += __shfl_down(v, off);
    aff[e] = v + br[e];                        // valid on lane 0
  }
  if (ln == 0) {
    float mx = aff[0];
#pragma unroll
    for (int e = 1; e < NR; e++) mx = fmaxf(mx, aff[e]);
    float p[NR]; float s = 0.f;
#pragma unroll
    for (int e = 0; e < NR; e++) { p[e] = expf(aff[e] - mx); s += p[e]; }
    float inv = 1.f / s;
    unsigned used = 0;
    for (int j = 0; j < TK; j++) {
      int be = -1; float bv = -1.f;
#pragma unroll
      for (int e = 0; e < NR; e++)
        if (!((used >> e) & 1u) && p[e] > bv) { bv = p[e]; be = e; }   // strict > : ties pick lowest idx (jax top_k)
      used |= 1u << be;
      topk_e[t * TK + j] = be;
      topk_g[t * TK + j] = bv * inv;           // softmax gate, NOT renormalized
      atomicAdd(&cnt[be], 1);
    }
  }
}

// segment layout: seg0 = shared0 rows [0,4096), seg1 = shared1 [4096,8192),
// seg 2+e = routed expert e, rows [8192 + prefix(cnt), ...)
__global__ void k_prefix(const int* __restrict__ cnt, int* __restrict__ segbase,
                         int* __restrict__ segcnt) {
  if (threadIdx.x == 0) {
    segbase[0] = 0;    segcnt[0] = T;
    segbase[1] = T;    segcnt[1] = T;
    int b = 2 * T;
    for (int e = 0; e < NR; e++) { segbase[2 + e] = b; segcnt[2 + e] = cnt[e]; b += cnt[e]; }
  }
}

__global__ void k_fill(const int* __restrict__ topk_e, const float* __restrict__ topk_g,
                       const int* __restrict__ segbase, int* __restrict__ fill,
                       int* __restrict__ rowtok, float* __restrict__ rowgate) {
  int t = blockIdx.x * 256 + threadIdx.x;
  if (t >= T) return;
  rowtok[t] = t;         rowgate[t] = 1.0f;       // shared expert 0
  rowtok[T + t] = t;     rowgate[T + t] = 1.0f;   // shared expert 1
  for (int j = 0; j < TK; j++) {
    int e   = topk_e[t * TK + j];
    float g = topk_g[t * TK + j];
    int p = atomicAdd(&fill[e], 1);
    int r = segbase[2 + e] + p;
    rowtok[r]  = t;
    rowgate[r] = g;
  }
}

// ---------------- grouped GEMMs ----------------
// 128x128 tile, BK=64, 4 waves in 2x2 of 64x64, mfma_f32_16x16x32_bf16.
// A frag: A[m=lane&15][k=quad*8+j]; B frag: B[k=quad*8+j][n=lane&15] (B stored transposed, K-contig).
// C/D: col = lane&15, row = quad*4 + reg.

// GEMM1: h[row] = gelu( xb[tok[row]] @ W1[seg] + b1[seg] )
__global__ __launch_bounds__(256) void k_gemm1(
    const unsigned short* __restrict__ xb, const unsigned short* __restrict__ w1b,
    const float* __restrict__ b1s, const float* __restrict__ b1r,
    const int* __restrict__ rowtok, const int* __restrict__ segbase,
    const int* __restrict__ segcnt, unsigned short* __restrict__ hbuf) {
  int seg = blockIdx.z;
  int cnt = segcnt[seg];
  int m0  = blockIdx.y * 128;
  if (m0 >= cnt) return;
  int n0  = blockIdx.x * 128;
  int sb  = segbase[seg];
  const unsigned short* Bw = w1b + (size_t)seg * H * H;
  const float* bias = (seg < 2) ? b1s + (size_t)seg * H : b1r + (size_t)(seg - 2) * H;

  __shared__ __align__(16) unsigned short Al[128 * 72];  // +8 bf16 pad: 2-way-free frag reads
  __shared__ __align__(16) unsigned short Bl[128 * 72];

  int tid = threadIdx.x;
  int wv = tid >> 6, ln = tid & 63;
  int rw = (wv >> 1) * 64, cw = (wv & 1) * 64;
  int quad = ln >> 4, l16 = ln & 15;
  int lrow = tid >> 3;          // 0..31 staging row within pass
  int lkc  = (tid & 7) * 8;     // 8 bf16 (16B) per thread

  const unsigned short* asrc[4];
  const unsigned short* bsrc[4];
#pragma unroll
  for (int p = 0; p < 4; p++) {
    int row = p * 32 + lrow;
    int gm  = m0 + row;
    int tok = (gm < cnt) ? rowtok[sb + gm] : 0;   // clamp padding to valid mem
    asrc[p] = xb + (size_t)tok * H + lkc;
    bsrc[p] = Bw + (size_t)(n0 + row) * H + lkc;
  }

  f32x4 acc[4][4];
#pragma unroll
  for (int i = 0; i < 4; i++)
#pragma unroll
    for (int j = 0; j < 4; j++) acc[i][j] = (f32x4){0.f, 0.f, 0.f, 0.f};

  for (int k0 = 0; k0 < H; k0 += 64) {
    __syncthreads();
#pragma unroll
    for (int p = 0; p < 4; p++) {
      int row = p * 32 + lrow;
      *reinterpret_cast<uint4*>(&Al[row * 72 + lkc]) = *reinterpret_cast<const uint4*>(asrc[p] + k0);
      *reinterpret_cast<uint4*>(&Bl[row * 72 + lkc]) = *reinterpret_cast<const uint4*>(bsrc[p] + k0);
    }
    __syncthreads();
#pragma unroll
    for (int kk = 0; kk < 64; kk += 32) {
      bf16x8 af[4], bfr[4];
#pragma unroll
      for (int i = 0; i < 4; i++)
        af[i] = *reinterpret_cast<const bf16x8*>(&Al[(rw + i * 16 + l16) * 72 + kk + quad * 8]);
#pragma unroll
      for (int j = 0; j < 4; j++)
        bfr[j] = *reinterpret_cast<const bf16x8*>(&Bl[(cw + j * 16 + l16) * 72 + kk + quad * 8]);
#pragma unroll
      for (int i = 0; i < 4; i++)
#pragma unroll
        for (int j = 0; j < 4; j++)
          acc[i][j] = __builtin_amdgcn_mfma_f32_16x16x32_bf16(af[i], bfr[j], acc[i][j], 0, 0, 0);
    }
  }

#pragma unroll
  for (int i = 0; i < 4; i++) {
#pragma unroll
    for (int r = 0; r < 4; r++) {
      int m = m0 + rw + i * 16 + quad * 4 + r;
      if (m >= cnt) continue;
      size_t ro = (size_t)(sb + m) * H;
#pragma unroll
      for (int j = 0; j < 4; j++) {
        int n = n0 + cw + j * 16 + l16;
        float v = acc[i][j][r] + bias[n];
        float g = 0.5f * v * (1.f + erff(v * 0.70710678118654752f));   // exact-erf GELU
        hbuf[ro + n] = f2bf(g);
      }
    }
  }
}

// GEMM2: out[tok[row]] += gate[row] * ( h[row] @ W2[seg] + b2[seg] )
__global__ __launch_bounds__(256) void k_gemm2(
    const unsigned short* __restrict__ hbuf, const unsigned short* __restrict__ w2b,
    const float* __restrict__ b2s, const float* __restrict__ b2r,
    const int* __restrict__ rowtok, const float* __restrict__ rowgate,
    const int* __restrict__ segbase, const int* __restrict__ segcnt,
    float* __restrict__ out) {
  int seg = blockIdx.z;
  int cnt = segcnt[seg];
  int m0  = blockIdx.y * 128;
  if (m0 >= cnt) return;
  int n0  = blockIdx.x * 128;
  int sb  = segbase[seg];
  const unsigned short* Bw = w2b + (size_t)seg * H * H;
  const float* bias = (seg < 2) ? b2s + (size_t)seg * H : b2r + (size_t)(seg - 2) * H;

  __shared__ __align__(16) unsigned short Al[128 * 72];
  __shared__ __align__(16) unsigned short Bl[128 * 72];

  int tid = threadIdx.x;
  int wv = tid >> 6, ln = tid & 63;
  int rw = (wv >> 1) * 64, cw = (wv & 1) * 64;
  int quad = ln >> 4, l16 = ln & 15;
  int lrow = tid >> 3;
  int lkc  = (tid & 7) * 8;

  const unsigned short* asrc[4];
  const unsigned short* bsrc[4];
#pragma unroll
  for (int p = 0; p < 4; p++) {
    int row = p * 32 + lrow;
    int ar  = sb + m0 + row;
    if (ar >= NROWS) ar = 0;                      // keep in-bounds for padding rows
    asrc[p] = hbuf + (size_t)ar * H + lkc;
    bsrc[p] = Bw + (size_t)(n0 + row) * H + lkc;
  }

  f32x4 acc[4][4];
#pragma unroll
  for (int i = 0; i < 4; i++)
#pragma unroll
    for (int j = 0; j < 4; j++) acc[i][j] = (f32x4){0.f, 0.f, 0.f, 0.f};

  for (int k0 = 0; k0 < H; k0 += 64) {
    __syncthreads();
#pragma unroll
    for (int p = 0; p < 4; p++) {
      int row = p * 32 + lrow;
      *reinterpret_cast<uint4*>(&Al[row * 72 + lkc]) = *reinterpret_cast<const uint4*>(asrc[p] + k0);
      *reinterpret_cast<uint4*>(&Bl[row * 72 + lkc]) = *reinterpret_cast<const uint4*>(bsrc[p] + k0);
    }
    __syncthreads();
#pragma unroll
    for (int kk = 0; kk < 64; kk += 32) {
      bf16x8 af[4], bfr[4];
#pragma unroll
      for (int i = 0; i < 4; i++)
        af[i] = *reinterpret_cast<const bf16x8*>(&Al[(rw + i * 16 + l16) * 72 + kk + quad * 8]);
#pragma unroll
      for (int j = 0; j < 4; j++)
        bfr[j] = *reinterpret_cast<const bf16x8*>(&Bl[(cw + j * 16 + l16) * 72 + kk + quad * 8]);
#pragma unroll
      for (int i = 0; i < 4; i++)
#pragma unroll
        for (int j = 0; j < 4; j++)
          acc[i][j] = __builtin_amdgcn_mfma_f32_16x16x32_bf16(af[i], bfr[j], acc[i][j], 0, 0, 0);
    }
  }

#pragma unroll
  for (int i = 0; i < 4; i++) {
#pragma unroll
    for (int r = 0; r < 4; r++) {
      int m = m0 + rw + i * 16 + quad * 4 + r;
      if (m >= cnt) continue;
      int grow  = sb + m;
      int tok   = rowtok[grow];
      float g   = rowgate[grow];
      float* orow = out + (size_t)tok * H;
#pragma unroll
      for (int j = 0; j < 4; j++) {
        int n = n0 + cw + j * 16 + l16;
        atomicAdd(&orow[n], g * (acc[i][j][r] + bias[n]));
      }
    }
  }
}

// ---------------- host launch ----------------
extern "C" void kernel_launch(void* const* d_in, const int* in_sizes, int n_in,
                              void* d_out, int out_size, void* d_ws, size_t ws_size,
                              hipStream_t stream) {
  const float* x   = (const float*)d_in[0];
  const float* W1s = (const float*)d_in[1];
  const float* b1s = (const float*)d_in[2];
  const float* W2s = (const float*)d_in[3];
  const float* b2s = (const float*)d_in[4];
  const float* W1r = (const float*)d_in[5];
  const float* b1r = (const float*)d_in[6];
  const float* W2r = (const float*)d_in[7];
  const float* b2r = (const float*)d_in[8];
  const float* Wr  = (const float*)d_in[9];
  const float* br  = (const float*)d_in[10];
  float* out = (float*)d_out;

  char* ws = (char*)d_ws;
  const size_t SZ_XB = (size_t)T * H * 2;
  const size_t SZ_WB = (size_t)NE * H * H * 2;
  const size_t SZ_H  = (size_t)NROWS * H * 2;
  size_t off = 0;
  unsigned short* xb   = (unsigned short*)(ws + off); off += SZ_XB;
  unsigned short* w1b  = (unsigned short*)(ws + off); off += SZ_WB;
  unsigned short* w2b  = (unsigned short*)(ws + off); off += SZ_WB;
  unsigned short* hbuf = (unsigned short*)(ws + off); off += SZ_H;
  int*   rowtok  = (int*)(ws + off);   off += NROWS * 4;
  float* rowgate = (float*)(ws + off); off += NROWS * 4;
  int*   topk_e  = (int*)(ws + off);   off += T * TK * 4;
  float* topk_g  = (float*)(ws + off); off += T * TK * 4;
  int*   cnt     = (int*)(ws + off);   off += 64;
  int*   fill    = (int*)(ws + off);   off += 64;
  int*   segbase = (int*)(ws + off);   off += 64;
  int*   segcnt  = (int*)(ws + off);   off += 64;

  hipLaunchKernelGGL(k_init, dim3(1), dim3(64), 0, stream, cnt, fill);
  hipLaunchKernelGGL(k_cast_x, dim3((T * H / 4) / 256), dim3(256), 0, stream, x, xb, out);
  hipLaunchKernelGGL(k_transpose, dim3(40, 40, 32), dim3(256), 0, stream,
                     W1s, W2s, W1r, W2r, w1b, w2b);
  hipLaunchKernelGGL(k_router, dim3(T), dim3(64), 0, stream, x, Wr, br, topk_e, topk_g, cnt);
  hipLaunchKernelGGL(k_prefix, dim3(1), dim3(1), 0, stream, cnt, segbase, segcnt);
  hipLaunchKernelGGL(k_fill, dim3(T / 256), dim3(256), 0, stream,
                     topk_e, topk_g, segbase, fill, rowtok, rowgate);
  hipLaunchKernelGGL(k_gemm1, dim3(10, 32, 16), dim3(256), 0, stream,
                     xb, w1b, b1s, b1r, rowtok, segbase, segcnt, hbuf);
  hipLaunchKernelGGL(k_gemm2, dim3(10, 32, 16), dim3(256), 0, stream,
                     hbuf, w2b, b2s, b2r, rowtok, rowgate, segbase, segcnt, out);
}

// Round 2
// 927.718 us; speedup vs baseline: 1.0871x; 1.0871x over previous
//
#include <hip/hip_runtime.h>
#include <hip/hip_bf16.h>
#include <math.h>

// ---------------- problem constants ----------------
#define H      1280          // hidden == intermediate
#define NE     16            // total experts (2 shared + 14 routed)
#define NR     14            // routed experts
#define TK     4             // top-k routed per token
#define T      4096          // tokens (B*S = 2*2048)
#define NROWS  24576         // 2*T shared rows + 4*T routed rows

typedef __bf16 bf16x8 __attribute__((ext_vector_type(8)));
typedef float  f32x4  __attribute__((ext_vector_type(4)));

__device__ __forceinline__ unsigned short f2bf(float f) {
  unsigned int u = __float_as_uint(f);
  u += 0x7fffu + ((u >> 16) & 1u);
  return (unsigned short)(u >> 16);
}
__device__ __forceinline__ float bf2f(unsigned short u) {
  return __uint_as_float(((unsigned int)u) << 16);
}

// async 16B global->LDS (m97 structure: LDS dest must be wave-uniform base + lane*16)
__device__ __forceinline__ void gll16(const unsigned short* g, unsigned short* l) {
  __builtin_amdgcn_global_load_lds(
      (const __attribute__((address_space(1))) void*)g,
      (__attribute__((address_space(3))) void*)l, 16, 0, 0);
}

// ---------------- small setup kernels ----------------
__global__ void k_init(int* cnt, int* fill) {
  int i = threadIdx.x;
  if (i < 16) { cnt[i] = 0; fill[i] = 0; }
}

// xb = bf16(x)
__global__ void k_cast_x(const float* __restrict__ x, unsigned short* __restrict__ xb) {
  int i = blockIdx.x * 256 + threadIdx.x;     // T*H/4 threads
  float4 v = reinterpret_cast<const float4*>(x)[i];
  ushort4 b;
  b.x = f2bf(v.x); b.y = f2bf(v.y); b.z = f2bf(v.z); b.w = f2bf(v.w);
  reinterpret_cast<ushort4*>(xb)[i] = b;
}

// Transpose+convert all 32 weight matrices: dst[n][k] = bf16(src[k][n]).
// 64x64 tile, float4 loads, ushort4 stores.
__global__ void k_transpose(const float* __restrict__ W1s, const float* __restrict__ W2s,
                            const float* __restrict__ W1r, const float* __restrict__ W2r,
                            unsigned short* __restrict__ w1b, unsigned short* __restrict__ w2b) {
  int mat = blockIdx.z;
  int fam = mat >> 4;       // 0 -> W1 family, 1 -> W2 family
  int e   = mat & 15;       // expert slot: 0,1 shared; 2..15 routed
  size_t msz = (size_t)H * H;
  const float* src;
  unsigned short* dst;
  if (fam == 0) {
    src = (e < 2) ? W1s + (size_t)e * msz : W1r + (size_t)(e - 2) * msz;
    dst = w1b + (size_t)e * msz;
  } else {
    src = (e < 2) ? W2s + (size_t)e * msz : W2r + (size_t)(e - 2) * msz;
    dst = w2b + (size_t)e * msz;
  }
  __shared__ unsigned short tile[64][68];     // [srcCol][srcRow]; 68-stride: 8B-aligned rows
  int tx = threadIdx.x & 15;                  // src col group (x4)
  int ty = threadIdx.x >> 4;                  // 0..15
  int bx = blockIdx.x * 64;                   // src col base
  int by = blockIdx.y * 64;                   // src row base
#pragma unroll
  for (int p = 0; p < 4; p++) {
    int r = p * 16 + ty;
    float4 v = *reinterpret_cast<const float4*>(&src[(size_t)(by + r) * H + bx + tx * 4]);
    tile[tx * 4 + 0][r] = f2bf(v.x);
    tile[tx * 4 + 1][r] = f2bf(v.y);
    tile[tx * 4 + 2][r] = f2bf(v.z);
    tile[tx * 4 + 3][r] = f2bf(v.w);
  }
  __syncthreads();
#pragma unroll
  for (int p = 0; p < 4; p++) {
    int n = p * 16 + ty;                      // src col / dst row offset
    ushort4 o;
    o.x = tile[n][tx * 4 + 0];
    o.y = tile[n][tx * 4 + 1];
    o.z = tile[n][tx * 4 + 2];
    o.w = tile[n][tx * 4 + 3];
    *reinterpret_cast<ushort4*>(&dst[(size_t)(bx + n) * H + by + tx * 4]) = o;
  }
}

// ---------------- router: logits -> softmax -> top4 ----------------
__global__ void k_router(const float* __restrict__ x, const float* __restrict__ Wr,
                         const float* __restrict__ br,
                         int* __restrict__ topk_e, float* __restrict__ topk_g,
                         int* __restrict__ cnt) {
  int t  = blockIdx.x;
  int ln = threadIdx.x;                        // 0..63
  float part[NR];
#pragma unroll
  for (int e = 0; e < NR; e++) part[e] = 0.f;
  const float* xr = x + (size_t)t * H;
  for (int k = ln; k < H; k += 64) {
    float xv = xr[k];
    const float* w = Wr + (size_t)k * NR;
#pragma unroll
    for (int e = 0; e < NR; e++) part[e] += xv * w[e];
  }
  float aff[NR];
#pragma unroll
  for (int e = 0; e < NR; e++) {
    float v = part[e];
#pragma unroll
    for (int off = 32; off; off >>= 1) v += __shfl_down(v, off);
    aff[e] = v + br[e];                        // valid on lane 0
  }
  if (ln == 0) {
    float mx = aff[0];
#pragma unroll
    for (int e = 1; e < NR; e++) mx = fmaxf(mx, aff[e]);
    float p[NR]; float s = 0.f;
#pragma unroll
    for (int e = 0; e < NR; e++) { p[e] = expf(aff[e] - mx); s += p[e]; }
    float inv = 1.f / s;
    unsigned used = 0;
    for (int j = 0; j < TK; j++) {
      int be = -1; float bv = -1.f;
#pragma unroll
      for (int e = 0; e < NR; e++)
        if (!((used >> e) & 1u) && p[e] > bv) { bv = p[e]; be = e; }  // ties -> lowest idx (jax top_k)
      used |= 1u << be;
      topk_e[t * TK + j] = be;
      topk_g[t * TK + j] = bv * inv;           // softmax gate, NOT renormalized
      atomicAdd(&cnt[be], 1);
    }
  }
}

// seg0 = shared0 rows [0,T), seg1 = shared1 [T,2T), seg 2+e = routed expert e
__global__ void k_prefix(const int* __restrict__ cnt, int* __restrict__ segbase,
                         int* __restrict__ segcnt) {
  if (threadIdx.x == 0) {
    segbase[0] = 0;    segcnt[0] = T;
    segbase[1] = T;    segcnt[1] = T;
    int b = 2 * T;
    for (int e = 0; e < NR; e++) { segbase[2 + e] = b; segcnt[2 + e] = cnt[e]; b += cnt[e]; }
  }
}

__global__ void k_fill(const int* __restrict__ topk_e,
                       const int* __restrict__ segbase, int* __restrict__ fill,
                       int* __restrict__ rowtok, int* __restrict__ tokrow) {
  int t = blockIdx.x * 256 + threadIdx.x;
  if (t >= T) return;
  rowtok[t]     = t;                            // shared expert 0
  rowtok[T + t] = t;                            // shared expert 1
  for (int j = 0; j < TK; j++) {
    int e = topk_e[t * TK + j];
    int p = atomicAdd(&fill[e], 1);
    int r = segbase[2 + e] + p;
    rowtok[r] = t;
    tokrow[t * TK + j] = r;                     // token -> its routed rows
  }
}

// ---------------- grouped GEMMs (m97 structure) ----------------
// 128x128 tile, BK=64, 4 waves 2x2 of 64x64, mfma_f32_16x16x32_bf16.
// LDS: unpadded stride-64 (global_load_lds needs dest = wave base + lane*16).
// A frag: A[m=lane&15][k=quad*8+j]; B frag: B[k][n=lane&15] (B stored N-major, K-contig).
// C/D: col = lane&15, row = quad*4 + reg.

// GEMM1: hbuf[row] = gelu( xb[rowtok[row]] @ W1[seg]^T + b1[seg] )
__global__ __launch_bounds__(256) void k_gemm1(
    const unsigned short* __restrict__ xb, const unsigned short* __restrict__ w1b,
    const float* __restrict__ b1s, const float* __restrict__ b1r,
    const int* __restrict__ rowtok, const int* __restrict__ segbase,
    const int* __restrict__ segcnt, unsigned short* __restrict__ hbuf) {
  int seg = blockIdx.z;
  int cnt = segcnt[seg];
  int m0  = blockIdx.y * 128;
  if (m0 >= cnt) return;
  int n0  = blockIdx.x * 128;
  int sb  = segbase[seg];
  const unsigned short* Bw = w1b + (size_t)seg * H * H;
  const float* bias = (seg < 2) ? b1s + (size_t)seg * H : b1r + (size_t)(seg - 2) * H;

  __shared__ __align__(16) unsigned short Al[128 * 64];
  __shared__ __align__(16) unsigned short Bl[128 * 64];

  int tid = threadIdx.x;
  int wv = tid >> 6, ln = tid & 63;
  int rw = (wv >> 1) * 64, cw = (wv & 1) * 64;
  int quad = ln >> 4, l16 = ln & 15;
  int lrow = tid >> 3;          // 0..31 staging row within pass
  int lkc  = (tid & 7) * 8;     // 8 bf16 (16B) per thread

  const unsigned short* asrc[4];
  const unsigned short* bsrc[4];
#pragma unroll
  for (int p = 0; p < 4; p++) {
    int row = p * 32 + lrow;
    int gm  = m0 + row;
    int tok = (gm < cnt) ? rowtok[sb + gm] : 0;
    asrc[p] = xb + (size_t)tok * H + lkc;
    bsrc[p] = Bw + (size_t)(n0 + row) * H + lkc;
  }

  f32x4 acc[4][4];
#pragma unroll
  for (int i = 0; i < 4; i++)
#pragma unroll
    for (int j = 0; j < 4; j++) acc[i][j] = (f32x4){0.f, 0.f, 0.f, 0.f};

  for (int k0 = 0; k0 < H; k0 += 64) {
    __syncthreads();
#pragma unroll
    for (int p = 0; p < 4; p++) {
      int row = p * 32 + lrow;
      gll16(asrc[p] + k0, &Al[row * 64 + lkc]);   // per-wave contiguous lane*16 dest
      gll16(bsrc[p] + k0, &Bl[row * 64 + lkc]);
    }
    __syncthreads();
#pragma unroll
    for (int kk = 0; kk < 64; kk += 32) {
      bf16x8 af[4], bfr[4];
#pragma unroll
      for (int i = 0; i < 4; i++)
        af[i] = *reinterpret_cast<const bf16x8*>(&Al[(rw + i * 16 + l16) * 64 + kk + quad * 8]);
#pragma unroll
      for (int j = 0; j < 4; j++)
        bfr[j] = *reinterpret_cast<const bf16x8*>(&Bl[(cw + j * 16 + l16) * 64 + kk + quad * 8]);
#pragma unroll
      for (int i = 0; i < 4; i++)
#pragma unroll
        for (int j = 0; j < 4; j++)
          acc[i][j] = __builtin_amdgcn_mfma_f32_16x16x32_bf16(af[i], bfr[j], acc[i][j], 0, 0, 0);
    }
  }

#pragma unroll
  for (int i = 0; i < 4; i++) {
#pragma unroll
    for (int r = 0; r < 4; r++) {
      int m = m0 + rw + i * 16 + quad * 4 + r;
      if (m >= cnt) continue;
      size_t ro = (size_t)(sb + m) * H;
#pragma unroll
      for (int j = 0; j < 4; j++) {
        int n = n0 + cw + j * 16 + l16;
        float v = acc[i][j][r] + bias[n];
        float g = 0.5f * v * (1.f + erff(v * 0.70710678118654752f));   // exact-erf GELU
        hbuf[ro + n] = f2bf(g);
      }
    }
  }
}

// GEMM2: rbuf[row] = bf16( hbuf[row] @ W2[seg]^T + b2[seg] )   (no atomics)
__global__ __launch_bounds__(256) void k_gemm2(
    const unsigned short* __restrict__ hbuf, const unsigned short* __restrict__ w2b,
    const float* __restrict__ b2s, const float* __restrict__ b2r,
    const int* __restrict__ segbase, const int* __restrict__ segcnt,
    unsigned short* __restrict__ rbuf) {
  int seg = blockIdx.z;
  int cnt = segcnt[seg];
  int m0  = blockIdx.y * 128;
  if (m0 >= cnt) return;
  int n0  = blockIdx.x * 128;
  int sb  = segbase[seg];
  const unsigned short* Bw = w2b + (size_t)seg * H * H;
  const float* bias = (seg < 2) ? b2s + (size_t)seg * H : b2r + (size_t)(seg - 2) * H;

  __shared__ __align__(16) unsigned short Al[128 * 64];
  __shared__ __align__(16) unsigned short Bl[128 * 64];

  int tid = threadIdx.x;
  int wv = tid >> 6, ln = tid & 63;
  int rw = (wv >> 1) * 64, cw = (wv & 1) * 64;
  int quad = ln >> 4, l16 = ln & 15;
  int lrow = tid >> 3;
  int lkc  = (tid & 7) * 8;

  const unsigned short* asrc[4];
  const unsigned short* bsrc[4];
#pragma unroll
  for (int p = 0; p < 4; p++) {
    int row = p * 32 + lrow;
    int ar  = sb + m0 + row;
    if (ar >= NROWS) ar = 0;                    // clamp padding rows in-bounds
    asrc[p] = hbuf + (size_t)ar * H + lkc;
    bsrc[p] = Bw + (size_t)(n0 + row) * H + lkc;
  }

  f32x4 acc[4][4];
#pragma unroll
  for (int i = 0; i < 4; i++)
#pragma unroll
    for (int j = 0; j < 4; j++) acc[i][j] = (f32x4){0.f, 0.f, 0.f, 0.f};

  for (int k0 = 0; k0 < H; k0 += 64) {
    __syncthreads();
#pragma unroll
    for (int p = 0; p < 4; p++) {
      int row = p * 32 + lrow;
      gll16(asrc[p] + k0, &Al[row * 64 + lkc]);
      gll16(bsrc[p] + k0, &Bl[row * 64 + lkc]);
    }
    __syncthreads();
#pragma unroll
    for (int kk = 0; kk < 64; kk += 32) {
      bf16x8 af[4], bfr[4];
#pragma unroll
      for (int i = 0; i < 4; i++)
        af[i] = *reinterpret_cast<const bf16x8*>(&Al[(rw + i * 16 + l16) * 64 + kk + quad * 8]);
#pragma unroll
      for (int j = 0; j < 4; j++)
        bfr[j] = *reinterpret_cast<const bf16x8*>(&Bl[(cw + j * 16 + l16) * 64 + kk + quad * 8]);
#pragma unroll
      for (int i = 0; i < 4; i++)
#pragma unroll
        for (int j = 0; j < 4; j++)
          acc[i][j] = __builtin_amdgcn_mfma_f32_16x16x32_bf16(af[i], bfr[j], acc[i][j], 0, 0, 0);
    }
  }

#pragma unroll
  for (int i = 0; i < 4; i++) {
#pragma unroll
    for (int r = 0; r < 4; r++) {
      int m = m0 + rw + i * 16 + quad * 4 + r;
      if (m >= cnt) continue;
      size_t ro = (size_t)(sb + m) * H;
#pragma unroll
      for (int j = 0; j < 4; j++) {
        int n = n0 + cw + j * 16 + l16;
        rbuf[ro + n] = f2bf(acc[i][j][r] + bias[n]);
      }
    }
  }
}

// out[t] = x[t] + rbuf[t] + rbuf[T+t] + sum_j gate_j * rbuf[tokrow[t][j]]
__global__ void k_combine(const float* __restrict__ x, const unsigned short* __restrict__ rbuf,
                          const int* __restrict__ tokrow, const float* __restrict__ topk_g,
                          float* __restrict__ out) {
  int i = blockIdx.x * 256 + threadIdx.x;      // T*H/4 threads
  int t = i / (H / 4);
  int c = (i - t * (H / 4)) * 4;
  size_t xo = (size_t)t * H + c;
  float4 acc = *reinterpret_cast<const float4*>(&x[xo]);
  {
    ushort4 u0 = *reinterpret_cast<const ushort4*>(&rbuf[(size_t)t * H + c]);
    ushort4 u1 = *reinterpret_cast<const ushort4*>(&rbuf[(size_t)(T + t) * H + c]);
    acc.x += bf2f(u0.x) + bf2f(u1.x);
    acc.y += bf2f(u0.y) + bf2f(u1.y);
    acc.z += bf2f(u0.z) + bf2f(u1.z);
    acc.w += bf2f(u0.w) + bf2f(u1.w);
  }
#pragma unroll
  for (int j = 0; j < TK; j++) {
    int r   = tokrow[t * TK + j];
    float g = topk_g[t * TK + j];
    ushort4 u = *reinterpret_cast<const ushort4*>(&rbuf[(size_t)r * H + c]);
    acc.x += g * bf2f(u.x);
    acc.y += g * bf2f(u.y);
    acc.z += g * bf2f(u.z);
    acc.w += g * bf2f(u.w);
  }
  *reinterpret_cast<float4*>(&out[xo]) = acc;
}

// ---------------- host launch ----------------
extern "C" void kernel_launch(void* const* d_in, const int* in_sizes, int n_in,
                              void* d_out, int out_size, void* d_ws, size_t ws_size,
                              hipStream_t stream) {
  const float* x   = (const float*)d_in[0];
  const float* W1s = (const float*)d_in[1];
  const float* b1s = (const float*)d_in[2];
  const float* W2s = (const float*)d_in[3];
  const float* b2s = (const float*)d_in[4];
  const float* W1r = (const float*)d_in[5];
  const float* b1r = (const float*)d_in[6];
  const float* W2r = (const float*)d_in[7];
  const float* b2r = (const float*)d_in[8];
  const float* Wr  = (const float*)d_in[9];
  const float* br  = (const float*)d_in[10];
  float* out = (float*)d_out;

  char* ws = (char*)d_ws;
  const size_t SZ_XB = (size_t)T * H * 2;            // 10.49 MB
  const size_t SZ_WB = (size_t)NE * H * H * 2;       // 52.43 MB each
  const size_t SZ_H  = (size_t)NROWS * H * 2;        // 62.91 MB
  size_t off = 0;
  unsigned short* xb   = (unsigned short*)(ws + off); off += SZ_XB;
  unsigned short* w1b  = (unsigned short*)(ws + off); off += SZ_WB;
  unsigned short* w2b  = (unsigned short*)(ws + off); off += SZ_WB;
  unsigned short* hbuf = (unsigned short*)(ws + off); off += SZ_H;
  int*   rowtok  = (int*)(ws + off);   off += NROWS * 4;
  int*   tokrow  = (int*)(ws + off);   off += T * TK * 4;
  int*   topk_e  = (int*)(ws + off);   off += T * TK * 4;
  float* topk_g  = (float*)(ws + off); off += T * TK * 4;
  int*   cnt     = (int*)(ws + off);   off += 64;
  int*   fill    = (int*)(ws + off);   off += 64;
  int*   segbase = (int*)(ws + off);   off += 64;
  int*   segcnt  = (int*)(ws + off);   off += 64;
  // rbuf aliases [xb][w1b] (exactly NROWS*H*2 bytes) — both dead once gemm2 runs.
  unsigned short* rbuf = (unsigned short*)ws;

  hipLaunchKernelGGL(k_init, dim3(1), dim3(64), 0, stream, cnt, fill);
  hipLaunchKernelGGL(k_cast_x, dim3((T * H / 4) / 256), dim3(256), 0, stream, x, xb);
  hipLaunchKernelGGL(k_transpose, dim3(20, 20, 32), dim3(256), 0, stream,
                     W1s, W2s, W1r, W2r, w1b, w2b);
  hipLaunchKernelGGL(k_router, dim3(T), dim3(64), 0, stream, x, Wr, br, topk_e, topk_g, cnt);
  hipLaunchKernelGGL(k_prefix, dim3(1), dim3(1), 0, stream, cnt, segbase, segcnt);
  hipLaunchKernelGGL(k_fill, dim3(T / 256), dim3(256), 0, stream,
                     topk_e, segbase, fill, rowtok, tokrow);
  hipLaunchKernelGGL(k_gemm1, dim3(10, 32, 16), dim3(256), 0, stream,
                     xb, w1b, b1s, b1r, rowtok, segbase, segcnt, hbuf);
  hipLaunchKernelGGL(k_gemm2, dim3(10, 32, 16), dim3(256), 0, stream,
                     hbuf, w2b, b2s, b2r, segbase, segcnt, rbuf);
  hipLaunchKernelGGL(k_combine, dim3((T * H / 4) / 256), dim3(256), 0, stream,
                     x, rbuf, tokrow, topk_g, out);
}

// Round 3
// 888.277 us; speedup vs baseline: 1.1354x; 1.0444x over previous
//
#include <hip/hip_runtime.h>
#include <hip/hip_bf16.h>
#include <math.h>

// ---------------- problem constants ----------------
#define H      1280          // hidden == intermediate
#define NE     16            // total experts (2 shared + 14 routed)
#define NR     14            // routed experts
#define TK     4             // top-k routed per token
#define T      4096          // tokens (B*S = 2*2048)
#define NROWS  24576         // 2*T shared rows + 4*T routed rows
#define MAXTILE 208          // >= sum ceil(segcnt/128) worst case (192 + 16)

typedef __bf16 bf16x8 __attribute__((ext_vector_type(8)));
typedef float  f32x4  __attribute__((ext_vector_type(4)));

__device__ __forceinline__ unsigned short f2bf(float f) {
  unsigned int u = __float_as_uint(f);
  u += 0x7fffu + ((u >> 16) & 1u);
  return (unsigned short)(u >> 16);
}
__device__ __forceinline__ float bf2f(unsigned short u) {
  return __uint_as_float(((unsigned int)u) << 16);
}

// async 16B global->LDS (LDS dest must be wave-uniform base + lane*16)
__device__ __forceinline__ void gll16(const unsigned short* g, unsigned short* l) {
  __builtin_amdgcn_global_load_lds(
      (const __attribute__((address_space(1))) void*)g,
      (__attribute__((address_space(3))) void*)l, 16, 0, 0);
}

// ---------------- small setup kernels ----------------
__global__ void k_init(int* cnt, int* fill) {
  int i = threadIdx.x;
  if (i < 16) { cnt[i] = 0; fill[i] = 0; }
}

// xb = bf16(x)
__global__ void k_cast_x(const float* __restrict__ x, unsigned short* __restrict__ xb) {
  int i = blockIdx.x * 256 + threadIdx.x;     // T*H/4 threads
  float4 v = reinterpret_cast<const float4*>(x)[i];
  ushort4 b;
  b.x = f2bf(v.x); b.y = f2bf(v.y); b.z = f2bf(v.z); b.w = f2bf(v.w);
  reinterpret_cast<ushort4*>(xb)[i] = b;
}

// Transpose+convert all 32 weight matrices: dst[n][k] = bf16(src[k][n]).
__global__ void k_transpose(const float* __restrict__ W1s, const float* __restrict__ W2s,
                            const float* __restrict__ W1r, const float* __restrict__ W2r,
                            unsigned short* __restrict__ w1b, unsigned short* __restrict__ w2b) {
  int mat = blockIdx.z;
  int fam = mat >> 4;       // 0 -> W1 family, 1 -> W2 family
  int e   = mat & 15;       // expert slot: 0,1 shared; 2..15 routed
  size_t msz = (size_t)H * H;
  const float* src;
  unsigned short* dst;
  if (fam == 0) {
    src = (e < 2) ? W1s + (size_t)e * msz : W1r + (size_t)(e - 2) * msz;
    dst = w1b + (size_t)e * msz;
  } else {
    src = (e < 2) ? W2s + (size_t)e * msz : W2r + (size_t)(e - 2) * msz;
    dst = w2b + (size_t)e * msz;
  }
  __shared__ unsigned short tile[64][68];     // [srcCol][srcRow]
  int tx = threadIdx.x & 15;                  // src col group (x4)
  int ty = threadIdx.x >> 4;                  // 0..15
  int bx = blockIdx.x * 64;                   // src col base
  int by = blockIdx.y * 64;                   // src row base
#pragma unroll
  for (int p = 0; p < 4; p++) {
    int r = p * 16 + ty;
    float4 v = *reinterpret_cast<const float4*>(&src[(size_t)(by + r) * H + bx + tx * 4]);
    tile[tx * 4 + 0][r] = f2bf(v.x);
    tile[tx * 4 + 1][r] = f2bf(v.y);
    tile[tx * 4 + 2][r] = f2bf(v.z);
    tile[tx * 4 + 3][r] = f2bf(v.w);
  }
  __syncthreads();
#pragma unroll
  for (int p = 0; p < 4; p++) {
    int n = p * 16 + ty;                      // src col / dst row offset
    ushort4 o;
    o.x = tile[n][tx * 4 + 0];
    o.y = tile[n][tx * 4 + 1];
    o.z = tile[n][tx * 4 + 2];
    o.w = tile[n][tx * 4 + 3];
    *reinterpret_cast<ushort4*>(&dst[(size_t)(bx + n) * H + by + tx * 4]) = o;
  }
}

// ---------------- router: logits -> softmax -> top4 ----------------
// 4 tokens per block, one wave each
__global__ void k_router(const float* __restrict__ x, const float* __restrict__ Wr,
                         const float* __restrict__ br,
                         int* __restrict__ topk_e, float* __restrict__ topk_g,
                         int* __restrict__ cnt) {
  int t  = blockIdx.x * 4 + (threadIdx.x >> 6);
  int ln = threadIdx.x & 63;
  float part[NR];
#pragma unroll
  for (int e = 0; e < NR; e++) part[e] = 0.f;
  const float* xr = x + (size_t)t * H;
  for (int k = ln; k < H; k += 64) {
    float xv = xr[k];
    const float* w = Wr + (size_t)k * NR;
#pragma unroll
    for (int e = 0; e < NR; e++) part[e] += xv * w[e];
  }
  float aff[NR];
#pragma unroll
  for (int e = 0; e < NR; e++) {
    float v = part[e];
#pragma unroll
    for (int off = 32; off; off >>= 1) v += __shfl_down(v, off);
    aff[e] = v + br[e];                        // valid on lane 0
  }
  if (ln == 0) {
    float mx = aff[0];
#pragma unroll
    for (int e = 1; e < NR; e++) mx = fmaxf(mx, aff[e]);
    float p[NR]; float s = 0.f;
#pragma unroll
    for (int e = 0; e < NR; e++) { p[e] = expf(aff[e] - mx); s += p[e]; }
    float inv = 1.f / s;
    unsigned used = 0;
    for (int j = 0; j < TK; j++) {
      int be = -1; float bv = -1.f;
#pragma unroll
      for (int e = 0; e < NR; e++)
        if (!((used >> e) & 1u) && p[e] > bv) { bv = p[e]; be = e; }  // ties -> lowest idx (jax top_k)
      used |= 1u << be;
      topk_e[t * TK + j] = be;
      topk_g[t * TK + j] = bv * inv;           // softmax gate, NOT renormalized
      atomicAdd(&cnt[be], 1);
    }
  }
}

// seg0 = shared0 [0,T), seg1 = shared1 [T,2T), seg 2+e = routed expert e.
// Also builds the compact m-tile table for the grouped GEMMs.
__global__ void k_prefix(const int* __restrict__ cnt, int* __restrict__ segbase,
                         int* __restrict__ segcnt, int* __restrict__ tile_seg,
                         int* __restrict__ tile_m0) {
  if (threadIdx.x == 0) {
    segbase[0] = 0;    segcnt[0] = T;
    segbase[1] = T;    segcnt[1] = T;
    int b = 2 * T;
    for (int e = 0; e < NR; e++) { segbase[2 + e] = b; segcnt[2 + e] = cnt[e]; b += cnt[e]; }
    int nt = 0;
    for (int s = 0; s < NE; s++)
      for (int m = 0; m < segcnt[s]; m += 128) { tile_seg[nt] = s; tile_m0[nt] = m; nt++; }
    for (int i = nt; i < MAXTILE; i++) { tile_seg[i] = -1; tile_m0[i] = 0; }
  }
}

__global__ void k_fill(const int* __restrict__ topk_e,
                       const int* __restrict__ segbase, int* __restrict__ fill,
                       int* __restrict__ rowtok, int* __restrict__ tokrow) {
  int t = blockIdx.x * 256 + threadIdx.x;
  if (t >= T) return;
  rowtok[t]     = t;                            // shared expert 0
  rowtok[T + t] = t;                            // shared expert 1
  for (int j = 0; j < TK; j++) {
    int e = topk_e[t * TK + j];
    int p = atomicAdd(&fill[e], 1);
    int r = segbase[2 + e] + p;
    rowtok[r] = t;
    tokrow[t * TK + j] = r;                     // token -> its routed rows
  }
}

// ---------------- grouped GEMMs ----------------
// 128x128 tile, BK=64, 4 waves 2x2 of 64x64, mfma_f32_16x16x32_bf16.
// LDS stride-64 unpadded (global_load_lds lane*16 dest), XOR chunk swizzle:
//   data chunk c of row r lives at LDS slot c ^ (r&7)   (chunk = 8 bf16 = 16B)
// so staging lane (r, slot s) fetches global chunk s ^ (r&7), and a fragment
// read of chunk q for row r reads slot q ^ (r&7)  ->  conflict-free ds_read_b128.
// A frag: A[m=lane&15][k=quad*8+j]; B frag: B[k][n=lane&15] (B stored N-major).
// C/D: col = lane&15, row = quad*4 + reg.

// GEMM1: hbuf[row] = gelu( xb[rowtok[row]] @ W1[seg]^T + b1[seg] )
__global__ __launch_bounds__(256) void k_gemm1(
    const unsigned short* __restrict__ xb, const unsigned short* __restrict__ w1b,
    const float* __restrict__ b1s, const float* __restrict__ b1r,
    const int* __restrict__ rowtok, const int* __restrict__ segbase,
    const int* __restrict__ segcnt, const int* __restrict__ tile_seg,
    const int* __restrict__ tile_m0, unsigned short* __restrict__ hbuf) {
  int seg = tile_seg[blockIdx.x];
  if (seg < 0) return;
  int m0  = tile_m0[blockIdx.x];
  int cnt = segcnt[seg];
  int n0  = blockIdx.y * 128;
  int sb  = segbase[seg];
  const unsigned short* Bw = w1b + (size_t)seg * H * H;
  const float* bias = (seg < 2) ? b1s + (size_t)seg * H : b1r + (size_t)(seg - 2) * H;

  __shared__ __align__(16) unsigned short Al[128 * 64];
  __shared__ __align__(16) unsigned short Bl[128 * 64];

  int tid = threadIdx.x;
  int wv = tid >> 6, ln = tid & 63;
  int rw = (wv >> 1) * 64, cw = (wv & 1) * 64;
  int quad = ln >> 4, l16 = ln & 15;
  int lrow = tid >> 3;                          // 0..31 staging row within pass
  int ldst = (tid & 7) * 8;                     // LDS slot (lane*16B contiguous)
  int lkc  = (((tid & 7) ^ (lrow & 7))) * 8;    // swizzled source chunk

  const unsigned short* asrc[4];
  const unsigned short* bsrc[4];
#pragma unroll
  for (int p = 0; p < 4; p++) {
    int row = p * 32 + lrow;                    // row&7 == lrow&7 (p*32 % 8 == 0)
    int gm  = m0 + row;
    int tok = (gm < cnt) ? rowtok[sb + gm] : 0;
    asrc[p] = xb + (size_t)tok * H + lkc;
    bsrc[p] = Bw + (size_t)(n0 + row) * H + lkc;
  }

  int xsw = (quad ^ (l16 & 7)) * 8;             // swizzled frag read base

  f32x4 acc[4][4];
#pragma unroll
  for (int i = 0; i < 4; i++)
#pragma unroll
    for (int j = 0; j < 4; j++) acc[i][j] = (f32x4){0.f, 0.f, 0.f, 0.f};

  for (int k0 = 0; k0 < H; k0 += 64) {
    __syncthreads();
#pragma unroll
    for (int p = 0; p < 4; p++) {
      int row = p * 32 + lrow;
      gll16(asrc[p] + k0, &Al[row * 64 + ldst]);
      gll16(bsrc[p] + k0, &Bl[row * 64 + ldst]);
    }
    __syncthreads();
#pragma unroll
    for (int kk = 0; kk < 64; kk += 32) {
      bf16x8 af[4], bfr[4];
#pragma unroll
      for (int i = 0; i < 4; i++)
        af[i] = *reinterpret_cast<const bf16x8*>(&Al[(rw + i * 16 + l16) * 64 + (xsw ^ kk)]);
#pragma unroll
      for (int j = 0; j < 4; j++)
        bfr[j] = *reinterpret_cast<const bf16x8*>(&Bl[(cw + j * 16 + l16) * 64 + (xsw ^ kk)]);
#pragma unroll
      for (int i = 0; i < 4; i++)
#pragma unroll
        for (int j = 0; j < 4; j++)
          acc[i][j] = __builtin_amdgcn_mfma_f32_16x16x32_bf16(af[i], bfr[j], acc[i][j], 0, 0, 0);
    }
  }

#pragma unroll
  for (int i = 0; i < 4; i++) {
#pragma unroll
    for (int r = 0; r < 4; r++) {
      int m = m0 + rw + i * 16 + quad * 4 + r;
      if (m >= cnt) continue;
      size_t ro = (size_t)(sb + m) * H;
#pragma unroll
      for (int j = 0; j < 4; j++) {
        int n = n0 + cw + j * 16 + l16;
        float v = acc[i][j][r] + bias[n];
        float g = 0.5f * v * (1.f + erff(v * 0.70710678118654752f));   // exact-erf GELU
        hbuf[ro + n] = f2bf(g);
      }
    }
  }
}

// GEMM2: rbuf[row] = bf16( hbuf[row] @ W2[seg]^T + b2[seg] )
__global__ __launch_bounds__(256) void k_gemm2(
    const unsigned short* __restrict__ hbuf, const unsigned short* __restrict__ w2b,
    const float* __restrict__ b2s, const float* __restrict__ b2r,
    const int* __restrict__ segbase, const int* __restrict__ segcnt,
    const int* __restrict__ tile_seg, const int* __restrict__ tile_m0,
    unsigned short* __restrict__ rbuf) {
  int seg = tile_seg[blockIdx.x];
  if (seg < 0) return;
  int m0  = tile_m0[blockIdx.x];
  int cnt = segcnt[seg];
  int n0  = blockIdx.y * 128;
  int sb  = segbase[seg];
  const unsigned short* Bw = w2b + (size_t)seg * H * H;
  const float* bias = (seg < 2) ? b2s + (size_t)seg * H : b2r + (size_t)(seg - 2) * H;

  __shared__ __align__(16) unsigned short Al[128 * 64];
  __shared__ __align__(16) unsigned short Bl[128 * 64];

  int tid = threadIdx.x;
  int wv = tid >> 6, ln = tid & 63;
  int rw = (wv >> 1) * 64, cw = (wv & 1) * 64;
  int quad = ln >> 4, l16 = ln & 15;
  int lrow = tid >> 3;
  int ldst = (tid & 7) * 8;
  int lkc  = (((tid & 7) ^ (lrow & 7))) * 8;

  const unsigned short* asrc[4];
  const unsigned short* bsrc[4];
#pragma unroll
  for (int p = 0; p < 4; p++) {
    int row = p * 32 + lrow;
    int ar  = sb + m0 + row;
    if (ar >= NROWS) ar = 0;                    // clamp padding rows in-bounds
    asrc[p] = hbuf + (size_t)ar * H + lkc;
    bsrc[p] = Bw + (size_t)(n0 + row) * H + lkc;
  }

  int xsw = (quad ^ (l16 & 7)) * 8;

  f32x4 acc[4][4];
#pragma unroll
  for (int i = 0; i < 4; i++)
#pragma unroll
    for (int j = 0; j < 4; j++) acc[i][j] = (f32x4){0.f, 0.f, 0.f, 0.f};

  for (int k0 = 0; k0 < H; k0 += 64) {
    __syncthreads();
#pragma unroll
    for (int p = 0; p < 4; p++) {
      int row = p * 32 + lrow;
      gll16(asrc[p] + k0, &Al[row * 64 + ldst]);
      gll16(bsrc[p] + k0, &Bl[row * 64 + ldst]);
    }
    __syncthreads();
#pragma unroll
    for (int kk = 0; kk < 64; kk += 32) {
      bf16x8 af[4], bfr[4];
#pragma unroll
      for (int i = 0; i < 4; i++)
        af[i] = *reinterpret_cast<const bf16x8*>(&Al[(rw + i * 16 + l16) * 64 + (xsw ^ kk)]);
#pragma unroll
      for (int j = 0; j < 4; j++)
        bfr[j] = *reinterpret_cast<const bf16x8*>(&Bl[(cw + j * 16 + l16) * 64 + (xsw ^ kk)]);
#pragma unroll
      for (int i = 0; i < 4; i++)
#pragma unroll
        for (int j = 0; j < 4; j++)
          acc[i][j] = __builtin_amdgcn_mfma_f32_16x16x32_bf16(af[i], bfr[j], acc[i][j], 0, 0, 0);
    }
  }

#pragma unroll
  for (int i = 0; i < 4; i++) {
#pragma unroll
    for (int r = 0; r < 4; r++) {
      int m = m0 + rw + i * 16 + quad * 4 + r;
      if (m >= cnt) continue;
      size_t ro = (size_t)(sb + m) * H;
#pragma unroll
      for (int j = 0; j < 4; j++) {
        int n = n0 + cw + j * 16 + l16;
        rbuf[ro + n] = f2bf(acc[i][j][r] + bias[n]);
      }
    }
  }
}

// out[t] = x[t] + rbuf[t] + rbuf[T+t] + sum_j gate_j * rbuf[tokrow[t][j]]
__global__ void k_combine(const float* __restrict__ x, const unsigned short* __restrict__ rbuf,
                          const int* __restrict__ tokrow, const float* __restrict__ topk_g,
                          float* __restrict__ out) {
  int i = blockIdx.x * 256 + threadIdx.x;      // T*H/4 threads
  int t = i / (H / 4);
  int c = (i - t * (H / 4)) * 4;
  size_t xo = (size_t)t * H + c;
  float4 acc = *reinterpret_cast<const float4*>(&x[xo]);
  {
    ushort4 u0 = *reinterpret_cast<const ushort4*>(&rbuf[(size_t)t * H + c]);
    ushort4 u1 = *reinterpret_cast<const ushort4*>(&rbuf[(size_t)(T + t) * H + c]);
    acc.x += bf2f(u0.x) + bf2f(u1.x);
    acc.y += bf2f(u0.y) + bf2f(u1.y);
    acc.z += bf2f(u0.z) + bf2f(u1.z);
    acc.w += bf2f(u0.w) + bf2f(u1.w);
  }
#pragma unroll
  for (int j = 0; j < TK; j++) {
    int r   = tokrow[t * TK + j];
    float g = topk_g[t * TK + j];
    ushort4 u = *reinterpret_cast<const ushort4*>(&rbuf[(size_t)r * H + c]);
    acc.x += g * bf2f(u.x);
    acc.y += g * bf2f(u.y);
    acc.z += g * bf2f(u.z);
    acc.w += g * bf2f(u.w);
  }
  *reinterpret_cast<float4*>(&out[xo]) = acc;
}

// ---------------- host launch ----------------
extern "C" void kernel_launch(void* const* d_in, const int* in_sizes, int n_in,
                              void* d_out, int out_size, void* d_ws, size_t ws_size,
                              hipStream_t stream) {
  const float* x   = (const float*)d_in[0];
  const float* W1s = (const float*)d_in[1];
  const float* b1s = (const float*)d_in[2];
  const float* W2s = (const float*)d_in[3];
  const float* b2s = (const float*)d_in[4];
  const float* W1r = (const float*)d_in[5];
  const float* b1r = (const float*)d_in[6];
  const float* W2r = (const float*)d_in[7];
  const float* b2r = (const float*)d_in[8];
  const float* Wr  = (const float*)d_in[9];
  const float* br  = (const float*)d_in[10];
  float* out = (float*)d_out;

  char* ws = (char*)d_ws;
  const size_t SZ_XB = (size_t)T * H * 2;            // 10.49 MB
  const size_t SZ_WB = (size_t)NE * H * H * 2;       // 52.43 MB each
  const size_t SZ_H  = (size_t)NROWS * H * 2;        // 62.91 MB
  size_t off = 0;
  unsigned short* xb   = (unsigned short*)(ws + off); off += SZ_XB;
  unsigned short* w1b  = (unsigned short*)(ws + off); off += SZ_WB;
  unsigned short* w2b  = (unsigned short*)(ws + off); off += SZ_WB;
  unsigned short* hbuf = (unsigned short*)(ws + off); off += SZ_H;
  int*   rowtok  = (int*)(ws + off);   off += NROWS * 4;
  int*   tokrow  = (int*)(ws + off);   off += T * TK * 4;
  int*   topk_e  = (int*)(ws + off);   off += T * TK * 4;
  float* topk_g  = (float*)(ws + off); off += T * TK * 4;
  int*   cnt     = (int*)(ws + off);   off += 64;
  int*   fill    = (int*)(ws + off);   off += 64;
  int*   segbase = (int*)(ws + off);   off += 64;
  int*   segcnt  = (int*)(ws + off);   off += 64;
  int*   tile_seg = (int*)(ws + off);  off += MAXTILE * 4;
  int*   tile_m0  = (int*)(ws + off);  off += MAXTILE * 4;
  // rbuf aliases [xb][w1b] (exactly NROWS*H*2 bytes) — both dead once gemm2 runs.
  unsigned short* rbuf = (unsigned short*)ws;

  hipLaunchKernelGGL(k_init, dim3(1), dim3(64), 0, stream, cnt, fill);
  hipLaunchKernelGGL(k_cast_x, dim3((T * H / 4) / 256), dim3(256), 0, stream, x, xb);
  hipLaunchKernelGGL(k_transpose, dim3(20, 20, 32), dim3(256), 0, stream,
                     W1s, W2s, W1r, W2r, w1b, w2b);
  hipLaunchKernelGGL(k_router, dim3(T / 4), dim3(256), 0, stream, x, Wr, br, topk_e, topk_g, cnt);
  hipLaunchKernelGGL(k_prefix, dim3(1), dim3(1), 0, stream, cnt, segbase, segcnt, tile_seg, tile_m0);
  hipLaunchKernelGGL(k_fill, dim3(T / 256), dim3(256), 0, stream,
                     topk_e, segbase, fill, rowtok, tokrow);
  hipLaunchKernelGGL(k_gemm1, dim3(MAXTILE, 10, 1), dim3(256), 0, stream,
                     xb, w1b, b1s, b1r, rowtok, segbase, segcnt, tile_seg, tile_m0, hbuf);
  hipLaunchKernelGGL(k_gemm2, dim3(MAXTILE, 10, 1), dim3(256), 0, stream,
                     hbuf, w2b, b2s, b2r, segbase, segcnt, tile_seg, tile_m0, rbuf);
  hipLaunchKernelGGL(k_combine, dim3((T * H / 4) / 256), dim3(256), 0, stream,
                     x, rbuf, tokrow, topk_g, out);
}

// Round 4
// 619.039 us; speedup vs baseline: 1.6292x; 1.4349x over previous
//
#include <hip/hip_runtime.h>
#include <hip/hip_bf16.h>
#include <math.h>

// ---------------- problem constants ----------------
#define H      1280          // hidden == intermediate
#define NE     16            // total experts (2 shared + 14 routed)
#define NR     14            // routed experts
#define TK     4             // top-k routed per token
#define T      4096          // tokens (B*S = 2*2048)
#define NROWS  24576         // 2*T shared rows + 4*T routed rows
#define MAXTILE 208          // >= sum ceil(segcnt/128) worst case

typedef __bf16 bf16x8 __attribute__((ext_vector_type(8)));
typedef float  f32x4  __attribute__((ext_vector_type(4)));

__device__ __forceinline__ unsigned short f2bf(float f) {
  unsigned int u = __float_as_uint(f);
  u += 0x7fffu + ((u >> 16) & 1u);
  return (unsigned short)(u >> 16);
}
__device__ __forceinline__ float bf2f(unsigned short u) {
  return __uint_as_float(((unsigned int)u) << 16);
}

// async 16B global->LDS (LDS dest must be wave-uniform base + lane*16)
__device__ __forceinline__ void gll16(const unsigned short* g, unsigned short* l) {
  __builtin_amdgcn_global_load_lds(
      (const __attribute__((address_space(1))) void*)g,
      (__attribute__((address_space(3))) void*)l, 16, 0, 0);
}

// ---------------- small setup kernels ----------------
__global__ void k_init(int* cnt, int* fill) {
  int i = threadIdx.x;
  if (i < 16) { cnt[i] = 0; fill[i] = 0; }
}

// xb = bf16(x)
__global__ void k_cast_x(const float* __restrict__ x, unsigned short* __restrict__ xb) {
  int i = blockIdx.x * 256 + threadIdx.x;     // T*H/4 threads
  float4 v = reinterpret_cast<const float4*>(x)[i];
  ushort4 b;
  b.x = f2bf(v.x); b.y = f2bf(v.y); b.z = f2bf(v.z); b.w = f2bf(v.w);
  reinterpret_cast<ushort4*>(xb)[i] = b;
}

// Transpose+convert all 32 weight matrices: dst[n][k] = bf16(src[k][n]).
__global__ void k_transpose(const float* __restrict__ W1s, const float* __restrict__ W2s,
                            const float* __restrict__ W1r, const float* __restrict__ W2r,
                            unsigned short* __restrict__ w1b, unsigned short* __restrict__ w2b) {
  int mat = blockIdx.z;
  int fam = mat >> 4;       // 0 -> W1 family, 1 -> W2 family
  int e   = mat & 15;       // expert slot: 0,1 shared; 2..15 routed
  size_t msz = (size_t)H * H;
  const float* src;
  unsigned short* dst;
  if (fam == 0) {
    src = (e < 2) ? W1s + (size_t)e * msz : W1r + (size_t)(e - 2) * msz;
    dst = w1b + (size_t)e * msz;
  } else {
    src = (e < 2) ? W2s + (size_t)e * msz : W2r + (size_t)(e - 2) * msz;
    dst = w2b + (size_t)e * msz;
  }
  __shared__ unsigned short tile[64][68];     // [srcCol][srcRow]
  int tx = threadIdx.x & 15;                  // src col group (x4)
  int ty = threadIdx.x >> 4;                  // 0..15
  int bx = blockIdx.x * 64;                   // src col base
  int by = blockIdx.y * 64;                   // src row base
#pragma unroll
  for (int p = 0; p < 4; p++) {
    int r = p * 16 + ty;
    float4 v = *reinterpret_cast<const float4*>(&src[(size_t)(by + r) * H + bx + tx * 4]);
    tile[tx * 4 + 0][r] = f2bf(v.x);
    tile[tx * 4 + 1][r] = f2bf(v.y);
    tile[tx * 4 + 2][r] = f2bf(v.z);
    tile[tx * 4 + 3][r] = f2bf(v.w);
  }
  __syncthreads();
#pragma unroll
  for (int p = 0; p < 4; p++) {
    int n = p * 16 + ty;                      // src col / dst row offset
    ushort4 o;
    o.x = tile[n][tx * 4 + 0];
    o.y = tile[n][tx * 4 + 1];
    o.z = tile[n][tx * 4 + 2];
    o.w = tile[n][tx * 4 + 3];
    *reinterpret_cast<ushort4*>(&dst[(size_t)(bx + n) * H + by + tx * 4]) = o;
  }
}

// ---------------- router: logits -> softmax -> top4 (NO atomics) ----------------
__global__ void k_router(const float* __restrict__ x, const float* __restrict__ Wr,
                         const float* __restrict__ br,
                         int* __restrict__ topk_e, float* __restrict__ topk_g) {
  int t  = blockIdx.x * 4 + (threadIdx.x >> 6);
  int ln = threadIdx.x & 63;
  float part[NR];
#pragma unroll
  for (int e = 0; e < NR; e++) part[e] = 0.f;
  const float* xr = x + (size_t)t * H;
  for (int k = ln; k < H; k += 64) {
    float xv = xr[k];
    const float* w = Wr + (size_t)k * NR;
#pragma unroll
    for (int e = 0; e < NR; e++) part[e] += xv * w[e];
  }
  float aff[NR];
#pragma unroll
  for (int e = 0; e < NR; e++) {
    float v = part[e];
#pragma unroll
    for (int off = 32; off; off >>= 1) v += __shfl_down(v, off);
    aff[e] = v + br[e];                        // valid on lane 0
  }
  if (ln == 0) {
    float mx = aff[0];
#pragma unroll
    for (int e = 1; e < NR; e++) mx = fmaxf(mx, aff[e]);
    float p[NR]; float s = 0.f;
#pragma unroll
    for (int e = 0; e < NR; e++) { p[e] = expf(aff[e] - mx); s += p[e]; }
    float inv = 1.f / s;
    unsigned used = 0;
    for (int j = 0; j < TK; j++) {
      int be = -1; float bv = -1.f;
#pragma unroll
      for (int e = 0; e < NR; e++)
        if (!((used >> e) & 1u) && p[e] > bv) { bv = p[e]; be = e; }  // ties -> lowest idx (jax top_k)
      used |= 1u << be;
      topk_e[t * TK + j] = be;
      topk_g[t * TK + j] = bv * inv;           // softmax gate, NOT renormalized
    }
  }
}

// histogram of topk_e -> cnt[], via LDS (224 global atomics total, not 16384)
__global__ void k_count(const int* __restrict__ topk_e, int* __restrict__ cnt) {
  __shared__ int hist[NR];
  int tid = threadIdx.x;
  if (tid < NR) hist[tid] = 0;
  __syncthreads();
  int t = blockIdx.x * 256 + tid;
#pragma unroll
  for (int j = 0; j < TK; j++)
    atomicAdd(&hist[topk_e[t * TK + j]], 1);
  __syncthreads();
  if (tid < NR) atomicAdd(&cnt[tid], hist[tid]);
}

// seg0 = shared0 [0,T), seg1 = shared1 [T,2T), seg 2+e = routed expert e.
// Also builds the compact m-tile table.
__global__ void k_prefix(const int* __restrict__ cnt, int* __restrict__ segbase,
                         int* __restrict__ segcnt, int* __restrict__ tile_seg,
                         int* __restrict__ tile_m0) {
  if (threadIdx.x == 0) {
    int sc[NE];
    sc[0] = T; sc[1] = T;
    for (int e = 0; e < NR; e++) sc[2 + e] = cnt[e];
    int b = 0;
    for (int s = 0; s < NE; s++) { segbase[s] = b; segcnt[s] = sc[s]; b += sc[s]; }
    int nt = 0;
    for (int s = 0; s < NE; s++)
      for (int m = 0; m < sc[s]; m += 128) { tile_seg[nt] = s; tile_m0[nt] = m; nt++; }
    for (int i = nt; i < MAXTILE; i++) { tile_seg[i] = -1; tile_m0[i] = 0; }
  }
}

// scatter tokens to segment rows; LDS-rank + per-block segment base (224 global atomics)
__global__ void k_fill(const int* __restrict__ topk_e,
                       const int* __restrict__ segbase, int* __restrict__ fill,
                       int* __restrict__ rowtok, int* __restrict__ tokrow) {
  __shared__ int lhist[NR];
  __shared__ int lbase[NR];
  int tid = threadIdx.x;
  if (tid < NR) lhist[tid] = 0;
  __syncthreads();
  int t = blockIdx.x * 256 + tid;
  rowtok[t]     = t;                            // shared expert 0
  rowtok[T + t] = t;                            // shared expert 1
  int e[TK], off[TK];
#pragma unroll
  for (int j = 0; j < TK; j++) {
    e[j]   = topk_e[t * TK + j];
    off[j] = atomicAdd(&lhist[e[j]], 1);        // intra-block rank (LDS atomic)
  }
  __syncthreads();
  if (tid < NR) lbase[tid] = atomicAdd(&fill[tid], lhist[tid]);  // block base
  __syncthreads();
#pragma unroll
  for (int j = 0; j < TK; j++) {
    int r = segbase[2 + e[j]] + lbase[e[j]] + off[j];
    rowtok[r] = t;
    tokrow[t * TK + j] = r;
  }
}

// ---------------- grouped GEMMs ----------------
// 128x128 tile, BK=64, 4 waves 2x2 of 64x64, mfma_f32_16x16x32_bf16.
// LDS stride-64 unpadded (global_load_lds lane*16 dest), XOR chunk swizzle:
//   data chunk c of row r lives at LDS slot c ^ (r&7)   (chunk = 8 bf16 = 16B)
// A frag: A[m=lane&15][k=quad*8+j]; B frag: B[k][n=lane&15] (B stored N-major).
// C/D: col = lane&15, row = quad*4 + reg.
// Grid = (10 n-tiles, MAXTILE): consecutive blocks share the A-tile (L2 reuse).

// GEMM1: hbuf[row] = gelu( xb[rowtok[row]] @ W1[seg]^T + b1[seg] )
__global__ __launch_bounds__(256) void k_gemm1(
    const unsigned short* __restrict__ xb, const unsigned short* __restrict__ w1b,
    const float* __restrict__ b1s, const float* __restrict__ b1r,
    const int* __restrict__ rowtok, const int* __restrict__ segbase,
    const int* __restrict__ segcnt, const int* __restrict__ tile_seg,
    const int* __restrict__ tile_m0, unsigned short* __restrict__ hbuf) {
  int seg = tile_seg[blockIdx.y];
  if (seg < 0) return;
  int m0  = tile_m0[blockIdx.y];
  int cnt = segcnt[seg];
  int n0  = blockIdx.x * 128;
  int sb  = segbase[seg];
  const unsigned short* Bw = w1b + (size_t)seg * H * H;
  const float* bias = (seg < 2) ? b1s + (size_t)seg * H : b1r + (size_t)(seg - 2) * H;

  __shared__ __align__(16) unsigned short Al[128 * 64];
  __shared__ __align__(16) unsigned short Bl[128 * 64];

  int tid = threadIdx.x;
  int wv = tid >> 6, ln = tid & 63;
  int rw = (wv >> 1) * 64, cw = (wv & 1) * 64;
  int quad = ln >> 4, l16 = ln & 15;
  int lrow = tid >> 3;                          // 0..31 staging row within pass
  int ldst = (tid & 7) * 8;                     // LDS slot (lane*16B contiguous)
  int lkc  = (((tid & 7) ^ (lrow & 7))) * 8;    // swizzled source chunk

  const unsigned short* asrc[4];
  const unsigned short* bsrc[4];
#pragma unroll
  for (int p = 0; p < 4; p++) {
    int row = p * 32 + lrow;                    // row&7 == lrow&7
    int gm  = m0 + row;
    int tok = (gm < cnt) ? rowtok[sb + gm] : 0;
    asrc[p] = xb + (size_t)tok * H + lkc;
    bsrc[p] = Bw + (size_t)(n0 + row) * H + lkc;
  }

  int xsw = (quad ^ (l16 & 7)) * 8;             // swizzled frag read base

  f32x4 acc[4][4];
#pragma unroll
  for (int i = 0; i < 4; i++)
#pragma unroll
    for (int j = 0; j < 4; j++) acc[i][j] = (f32x4){0.f, 0.f, 0.f, 0.f};

  for (int k0 = 0; k0 < H; k0 += 64) {
    __syncthreads();
#pragma unroll
    for (int p = 0; p < 4; p++) {
      int row = p * 32 + lrow;
      gll16(asrc[p] + k0, &Al[row * 64 + ldst]);
      gll16(bsrc[p] + k0, &Bl[row * 64 + ldst]);
    }
    __syncthreads();
#pragma unroll
    for (int kk = 0; kk < 64; kk += 32) {
      bf16x8 af[4], bfr[4];
#pragma unroll
      for (int i = 0; i < 4; i++)
        af[i] = *reinterpret_cast<const bf16x8*>(&Al[(rw + i * 16 + l16) * 64 + (xsw ^ kk)]);
#pragma unroll
      for (int j = 0; j < 4; j++)
        bfr[j] = *reinterpret_cast<const bf16x8*>(&Bl[(cw + j * 16 + l16) * 64 + (xsw ^ kk)]);
#pragma unroll
      for (int i = 0; i < 4; i++)
#pragma unroll
        for (int j = 0; j < 4; j++)
          acc[i][j] = __builtin_amdgcn_mfma_f32_16x16x32_bf16(af[i], bfr[j], acc[i][j], 0, 0, 0);
    }
  }

#pragma unroll
  for (int i = 0; i < 4; i++) {
#pragma unroll
    for (int r = 0; r < 4; r++) {
      int m = m0 + rw + i * 16 + quad * 4 + r;
      if (m >= cnt) continue;
      size_t ro = (size_t)(sb + m) * H;
#pragma unroll
      for (int j = 0; j < 4; j++) {
        int n = n0 + cw + j * 16 + l16;
        float v = acc[i][j][r] + bias[n];
        float g = 0.5f * v * (1.f + erff(v * 0.70710678118654752f));   // exact-erf GELU
        hbuf[ro + n] = f2bf(g);
      }
    }
  }
}

// GEMM2: rbuf[row] = bf16( hbuf[row] @ W2[seg]^T + b2[seg] )
__global__ __launch_bounds__(256) void k_gemm2(
    const unsigned short* __restrict__ hbuf, const unsigned short* __restrict__ w2b,
    const float* __restrict__ b2s, const float* __restrict__ b2r,
    const int* __restrict__ segbase, const int* __restrict__ segcnt,
    const int* __restrict__ tile_seg, const int* __restrict__ tile_m0,
    unsigned short* __restrict__ rbuf) {
  int seg = tile_seg[blockIdx.y];
  if (seg < 0) return;
  int m0  = tile_m0[blockIdx.y];
  int cnt = segcnt[seg];
  int n0  = blockIdx.x * 128;
  int sb  = segbase[seg];
  const unsigned short* Bw = w2b + (size_t)seg * H * H;
  const float* bias = (seg < 2) ? b2s + (size_t)seg * H : b2r + (size_t)(seg - 2) * H;

  __shared__ __align__(16) unsigned short Al[128 * 64];
  __shared__ __align__(16) unsigned short Bl[128 * 64];

  int tid = threadIdx.x;
  int wv = tid >> 6, ln = tid & 63;
  int rw = (wv >> 1) * 64, cw = (wv & 1) * 64;
  int quad = ln >> 4, l16 = ln & 15;
  int lrow = tid >> 3;
  int ldst = (tid & 7) * 8;
  int lkc  = (((tid & 7) ^ (lrow & 7))) * 8;

  const unsigned short* asrc[4];
  const unsigned short* bsrc[4];
#pragma unroll
  for (int p = 0; p < 4; p++) {
    int row = p * 32 + lrow;
    int ar  = sb + m0 + row;
    if (ar >= NROWS) ar = 0;                    // clamp padding rows in-bounds
    asrc[p] = hbuf + (size_t)ar * H + lkc;
    bsrc[p] = Bw + (size_t)(n0 + row) * H + lkc;
  }

  int xsw = (quad ^ (l16 & 7)) * 8;

  f32x4 acc[4][4];
#pragma unroll
  for (int i = 0; i < 4; i++)
#pragma unroll
    for (int j = 0; j < 4; j++) acc[i][j] = (f32x4){0.f, 0.f, 0.f, 0.f};

  for (int k0 = 0; k0 < H; k0 += 64) {
    __syncthreads();
#pragma unroll
    for (int p = 0; p < 4; p++) {
      int row = p * 32 + lrow;
      gll16(asrc[p] + k0, &Al[row * 64 + ldst]);
      gll16(bsrc[p] + k0, &Bl[row * 64 + ldst]);
    }
    __syncthreads();
#pragma unroll
    for (int kk = 0; kk < 64; kk += 32) {
      bf16x8 af[4], bfr[4];
#pragma unroll
      for (int i = 0; i < 4; i++)
        af[i] = *reinterpret_cast<const bf16x8*>(&Al[(rw + i * 16 + l16) * 64 + (xsw ^ kk)]);
#pragma unroll
      for (int j = 0; j < 4; j++)
        bfr[j] = *reinterpret_cast<const bf16x8*>(&Bl[(cw + j * 16 + l16) * 64 + (xsw ^ kk)]);
#pragma unroll
      for (int i = 0; i < 4; i++)
#pragma unroll
        for (int j = 0; j < 4; j++)
          acc[i][j] = __builtin_amdgcn_mfma_f32_16x16x32_bf16(af[i], bfr[j], acc[i][j], 0, 0, 0);
    }
  }

#pragma unroll
  for (int i = 0; i < 4; i++) {
#pragma unroll
    for (int r = 0; r < 4; r++) {
      int m = m0 + rw + i * 16 + quad * 4 + r;
      if (m >= cnt) continue;
      size_t ro = (size_t)(sb + m) * H;
#pragma unroll
      for (int j = 0; j < 4; j++) {
        int n = n0 + cw + j * 16 + l16;
        rbuf[ro + n] = f2bf(acc[i][j][r] + bias[n]);
      }
    }
  }
}

// out[t] = x[t] + rbuf[t] + rbuf[T+t] + sum_j gate_j * rbuf[tokrow[t][j]]
__global__ void k_combine(const float* __restrict__ x, const unsigned short* __restrict__ rbuf,
                          const int* __restrict__ tokrow, const float* __restrict__ topk_g,
                          float* __restrict__ out) {
  int i = blockIdx.x * 256 + threadIdx.x;      // T*H/4 threads
  int t = i / (H / 4);
  int c = (i - t * (H / 4)) * 4;
  size_t xo = (size_t)t * H + c;
  float4 acc = *reinterpret_cast<const float4*>(&x[xo]);
  {
    ushort4 u0 = *reinterpret_cast<const ushort4*>(&rbuf[(size_t)t * H + c]);
    ushort4 u1 = *reinterpret_cast<const ushort4*>(&rbuf[(size_t)(T + t) * H + c]);
    acc.x += bf2f(u0.x) + bf2f(u1.x);
    acc.y += bf2f(u0.y) + bf2f(u1.y);
    acc.z += bf2f(u0.z) + bf2f(u1.z);
    acc.w += bf2f(u0.w) + bf2f(u1.w);
  }
#pragma unroll
  for (int j = 0; j < TK; j++) {
    int r   = tokrow[t * TK + j];
    float g = topk_g[t * TK + j];
    ushort4 u = *reinterpret_cast<const ushort4*>(&rbuf[(size_t)r * H + c]);
    acc.x += g * bf2f(u.x);
    acc.y += g * bf2f(u.y);
    acc.z += g * bf2f(u.z);
    acc.w += g * bf2f(u.w);
  }
  *reinterpret_cast<float4*>(&out[xo]) = acc;
}

// ---------------- host launch ----------------
extern "C" void kernel_launch(void* const* d_in, const int* in_sizes, int n_in,
                              void* d_out, int out_size, void* d_ws, size_t ws_size,
                              hipStream_t stream) {
  const float* x   = (const float*)d_in[0];
  const float* W1s = (const float*)d_in[1];
  const float* b1s = (const float*)d_in[2];
  const float* W2s = (const float*)d_in[3];
  const float* b2s = (const float*)d_in[4];
  const float* W1r = (const float*)d_in[5];
  const float* b1r = (const float*)d_in[6];
  const float* W2r = (const float*)d_in[7];
  const float* b2r = (const float*)d_in[8];
  const float* Wr  = (const float*)d_in[9];
  const float* br  = (const float*)d_in[10];
  float* out = (float*)d_out;

  char* ws = (char*)d_ws;
  const size_t SZ_XB = (size_t)T * H * 2;            // 10.49 MB
  const size_t SZ_WB = (size_t)NE * H * H * 2;       // 52.43 MB each
  const size_t SZ_H  = (size_t)NROWS * H * 2;        // 62.91 MB
  size_t off = 0;
  unsigned short* xb   = (unsigned short*)(ws + off); off += SZ_XB;
  unsigned short* w1b  = (unsigned short*)(ws + off); off += SZ_WB;
  unsigned short* w2b  = (unsigned short*)(ws + off); off += SZ_WB;
  unsigned short* hbuf = (unsigned short*)(ws + off); off += SZ_H;
  int*   rowtok  = (int*)(ws + off);   off += NROWS * 4;
  int*   tokrow  = (int*)(ws + off);   off += T * TK * 4;
  int*   topk_e  = (int*)(ws + off);   off += T * TK * 4;
  float* topk_g  = (float*)(ws + off); off += T * TK * 4;
  int*   cnt     = (int*)(ws + off);   off += 64;
  int*   fill    = (int*)(ws + off);   off += 64;
  int*   segbase = (int*)(ws + off);   off += 64;
  int*   segcnt  = (int*)(ws + off);   off += 64;
  int*   tile_seg = (int*)(ws + off);  off += MAXTILE * 4;
  int*   tile_m0  = (int*)(ws + off);  off += MAXTILE * 4;
  // rbuf aliases [xb][w1b] (exactly NROWS*H*2 bytes) — both dead once gemm2 runs.
  unsigned short* rbuf = (unsigned short*)ws;

  hipLaunchKernelGGL(k_init, dim3(1), dim3(64), 0, stream, cnt, fill);
  hipLaunchKernelGGL(k_cast_x, dim3((T * H / 4) / 256), dim3(256), 0, stream, x, xb);
  hipLaunchKernelGGL(k_transpose, dim3(20, 20, 32), dim3(256), 0, stream,
                     W1s, W2s, W1r, W2r, w1b, w2b);
  hipLaunchKernelGGL(k_router, dim3(T / 4), dim3(256), 0, stream, x, Wr, br, topk_e, topk_g);
  hipLaunchKernelGGL(k_count, dim3(T / 256), dim3(256), 0, stream, topk_e, cnt);
  hipLaunchKernelGGL(k_prefix, dim3(1), dim3(1), 0, stream, cnt, segbase, segcnt, tile_seg, tile_m0);
  hipLaunchKernelGGL(k_fill, dim3(T / 256), dim3(256), 0, stream,
                     topk_e, segbase, fill, rowtok, tokrow);
  hipLaunchKernelGGL(k_gemm1, dim3(10, MAXTILE, 1), dim3(256), 0, stream,
                     xb, w1b, b1s, b1r, rowtok, segbase, segcnt, tile_seg, tile_m0, hbuf);
  hipLaunchKernelGGL(k_gemm2, dim3(10, MAXTILE, 1), dim3(256), 0, stream,
                     hbuf, w2b, b2s, b2r, segbase, segcnt, tile_seg, tile_m0, rbuf);
  hipLaunchKernelGGL(k_combine, dim3((T * H / 4) / 256), dim3(256), 0, stream,
                     x, rbuf, tokrow, topk_g, out);
}

// Round 5
// 610.975 us; speedup vs baseline: 1.6507x; 1.0132x over previous
//
#include <hip/hip_runtime.h>
#include <hip/hip_bf16.h>
#include <math.h>

// ---------------- problem constants ----------------
#define H      1280          // hidden == intermediate
#define NE     16            // total experts (2 shared + 14 routed)
#define NR     14            // routed experts
#define TK     4             // top-k routed per token
#define T      4096          // tokens (B*S = 2*2048)
#define NROWS  24576         // 2*T shared rows + 4*T routed rows
#define MAXT   112           // >= sum ceil(segcnt/256) worst case (32 shared + 77 routed)

typedef __bf16 bf16x8 __attribute__((ext_vector_type(8)));
typedef float  f32x4  __attribute__((ext_vector_type(4)));
typedef unsigned short us8 __attribute__((ext_vector_type(8)));

__device__ __forceinline__ unsigned short f2bf(float f) {
  unsigned int u = __float_as_uint(f);
  u += 0x7fffu + ((u >> 16) & 1u);
  return (unsigned short)(u >> 16);
}
__device__ __forceinline__ float bf2f(unsigned short u) {
  return __uint_as_float(((unsigned int)u) << 16);
}

// async 16B global->LDS (LDS dest must be wave-uniform base + lane*16)
__device__ __forceinline__ void gll16(const unsigned short* g, unsigned short* l) {
  __builtin_amdgcn_global_load_lds(
      (const __attribute__((address_space(1))) void*)g,
      (__attribute__((address_space(3))) void*)l, 16, 0, 0);
}

// ---------------- small setup kernels ----------------
__global__ void k_init(int* cnt, int* fill) {
  int i = threadIdx.x;
  if (i < 16) { cnt[i] = 0; fill[i] = 0; }
}

// xb = bf16(x)
__global__ void k_cast_x(const float* __restrict__ x, unsigned short* __restrict__ xb) {
  int i = blockIdx.x * 256 + threadIdx.x;     // T*H/4 threads
  float4 v = reinterpret_cast<const float4*>(x)[i];
  ushort4 b;
  b.x = f2bf(v.x); b.y = f2bf(v.y); b.z = f2bf(v.z); b.w = f2bf(v.w);
  reinterpret_cast<ushort4*>(xb)[i] = b;
}

// Transpose+convert all 32 weight matrices: dst[n][k] = bf16(src[k][n]).
// 64x64 tile; float4 loads, ushort8 (16B) stores. LDS row stride 72 -> 144 B (16B aligned).
__global__ void k_transpose(const float* __restrict__ W1s, const float* __restrict__ W2s,
                            const float* __restrict__ W1r, const float* __restrict__ W2r,
                            unsigned short* __restrict__ w1b, unsigned short* __restrict__ w2b) {
  int mat = blockIdx.z;
  int fam = mat >> 4;       // 0 -> W1 family, 1 -> W2 family
  int e   = mat & 15;       // expert slot: 0,1 shared; 2..15 routed
  size_t msz = (size_t)H * H;
  const float* src;
  unsigned short* dst;
  if (fam == 0) {
    src = (e < 2) ? W1s + (size_t)e * msz : W1r + (size_t)(e - 2) * msz;
    dst = w1b + (size_t)e * msz;
  } else {
    src = (e < 2) ? W2s + (size_t)e * msz : W2r + (size_t)(e - 2) * msz;
    dst = w2b + (size_t)e * msz;
  }
  __shared__ unsigned short tile[64][72];     // [srcCol][srcRow]
  int tx = threadIdx.x & 15;                  // src col group (x4)
  int ty = threadIdx.x >> 4;                  // 0..15
  int bx = blockIdx.x * 64;                   // src col base
  int by = blockIdx.y * 64;                   // src row base
#pragma unroll
  for (int p = 0; p < 4; p++) {
    int r = p * 16 + ty;
    float4 v = *reinterpret_cast<const float4*>(&src[(size_t)(by + r) * H + bx + tx * 4]);
    tile[tx * 4 + 0][r] = f2bf(v.x);
    tile[tx * 4 + 1][r] = f2bf(v.y);
    tile[tx * 4 + 2][r] = f2bf(v.z);
    tile[tx * 4 + 3][r] = f2bf(v.w);
  }
  __syncthreads();
  int tx8 = threadIdx.x & 7;                  // dst col group (x8)
  int rr  = threadIdx.x >> 3;                 // 0..31
#pragma unroll
  for (int p = 0; p < 2; p++) {
    int n = p * 32 + rr;                      // src col / dst row offset
    us8 o = *reinterpret_cast<const us8*>(&tile[n][tx8 * 8]);
    *reinterpret_cast<us8*>(&dst[(size_t)(bx + n) * H + by + tx8 * 8]) = o;
  }
}

// ---------------- router: logits -> softmax -> top4 (NO global atomics) ----------------
__global__ void k_router(const float* __restrict__ x, const float* __restrict__ Wr,
                         const float* __restrict__ br,
                         int* __restrict__ topk_e, float* __restrict__ topk_g) {
  int t  = blockIdx.x * 4 + (threadIdx.x >> 6);
  int ln = threadIdx.x & 63;
  float part[NR];
#pragma unroll
  for (int e = 0; e < NR; e++) part[e] = 0.f;
  const float* xr = x + (size_t)t * H;
  for (int k = ln; k < H; k += 64) {
    float xv = xr[k];
    const float* w = Wr + (size_t)k * NR;
#pragma unroll
    for (int e = 0; e < NR; e++) part[e] += xv * w[e];
  }
  float aff[NR];
#pragma unroll
  for (int e = 0; e < NR; e++) {
    float v = part[e];
#pragma unroll
    for (int off = 32; off; off >>= 1) v += __shfl_down(v, off);
    aff[e] = v + br[e];                        // valid on lane 0
  }
  if (ln == 0) {
    float mx = aff[0];
#pragma unroll
    for (int e = 1; e < NR; e++) mx = fmaxf(mx, aff[e]);
    float p[NR]; float s = 0.f;
#pragma unroll
    for (int e = 0; e < NR; e++) { p[e] = expf(aff[e] - mx); s += p[e]; }
    float inv = 1.f / s;
    unsigned used = 0;
    for (int j = 0; j < TK; j++) {
      int be = -1; float bv = -1.f;
#pragma unroll
      for (int e = 0; e < NR; e++)
        if (!((used >> e) & 1u) && p[e] > bv) { bv = p[e]; be = e; }  // ties -> lowest idx (jax top_k)
      used |= 1u << be;
      topk_e[t * TK + j] = be;
      topk_g[t * TK + j] = bv * inv;           // softmax gate, NOT renormalized
    }
  }
}

// histogram of topk_e -> cnt[] via LDS (224 global atomics total)
__global__ void k_count(const int* __restrict__ topk_e, int* __restrict__ cnt) {
  __shared__ int hist[NR];
  int tid = threadIdx.x;
  if (tid < NR) hist[tid] = 0;
  __syncthreads();
  int t = blockIdx.x * 256 + tid;
#pragma unroll
  for (int j = 0; j < TK; j++)
    atomicAdd(&hist[topk_e[t * TK + j]], 1);
  __syncthreads();
  if (tid < NR) atomicAdd(&cnt[tid], hist[tid]);
}

// seg0 = shared0 [0,T), seg1 = shared1 [T,2T), seg 2+e = routed expert e.
// Builds the compact 256-row m-tile table.
__global__ void k_prefix(const int* __restrict__ cnt, int* __restrict__ segbase,
                         int* __restrict__ segcnt, int* __restrict__ tile_seg,
                         int* __restrict__ tile_m0) {
  if (threadIdx.x == 0) {
    int sc[NE];
    sc[0] = T; sc[1] = T;
    for (int e = 0; e < NR; e++) sc[2 + e] = cnt[e];
    int b = 0;
    for (int s = 0; s < NE; s++) { segbase[s] = b; segcnt[s] = sc[s]; b += sc[s]; }
    int nt = 0;
    for (int s = 0; s < NE; s++)
      for (int m = 0; m < sc[s]; m += 256) { tile_seg[nt] = s; tile_m0[nt] = m; nt++; }
    for (int i = nt; i < MAXT; i++) { tile_seg[i] = -1; tile_m0[i] = 0; }
  }
}

// scatter tokens to segment rows; LDS ranks + 224 global atomics
__global__ void k_fill(const int* __restrict__ topk_e,
                       const int* __restrict__ segbase, int* __restrict__ fill,
                       int* __restrict__ rowtok, int* __restrict__ tokrow) {
  __shared__ int lhist[NR];
  __shared__ int lbase[NR];
  int tid = threadIdx.x;
  if (tid < NR) lhist[tid] = 0;
  __syncthreads();
  int t = blockIdx.x * 256 + tid;
  rowtok[t]     = t;                            // shared expert 0
  rowtok[T + t] = t;                            // shared expert 1
  int e[TK], off[TK];
#pragma unroll
  for (int j = 0; j < TK; j++) {
    e[j]   = topk_e[t * TK + j];
    off[j] = atomicAdd(&lhist[e[j]], 1);        // intra-block rank (LDS atomic)
  }
  __syncthreads();
  if (tid < NR) lbase[tid] = atomicAdd(&fill[tid], lhist[tid]);  // block base
  __syncthreads();
#pragma unroll
  for (int j = 0; j < TK; j++) {
    int r = segbase[2 + e[j]] + lbase[e[j]] + off[j];
    rowtok[r] = t;
    tokrow[t * TK + j] = r;
  }
}

// ---------------- grouped GEMMs ----------------
// 256x256 tile, BK=64, 512 threads = 8 waves (2 row groups x 4 col groups,
// each wave 128 rows x 64 cols), mfma_f32_16x16x32_bf16.
// LDS stride-64 unpadded (global_load_lds lane*16 dest), XOR chunk swizzle:
//   data chunk c of row r lives at LDS slot c ^ (r&7)  (chunk = 8 bf16 = 16B).
// A frag: A[m=lane&15][k=quad*8+j]; B frag: B[k][n=lane&15] (B stored N-major).
// C/D: col = lane&15, row = quad*4 + reg.
// 64 KB LDS -> 1-2 blocks/CU; 4x arithmetic intensity vs 128-tile.

// GEMM1: hbuf[row] = gelu( xb[rowtok[row]] @ W1[seg]^T + b1[seg] )
__global__ __launch_bounds__(512, 2) void k_gemm1(
    const unsigned short* __restrict__ xb, const unsigned short* __restrict__ w1b,
    const float* __restrict__ b1s, const float* __restrict__ b1r,
    const int* __restrict__ rowtok, const int* __restrict__ segbase,
    const int* __restrict__ segcnt, const int* __restrict__ tile_seg,
    const int* __restrict__ tile_m0, unsigned short* __restrict__ hbuf) {
  int seg = tile_seg[blockIdx.y];
  if (seg < 0) return;
  int m0  = tile_m0[blockIdx.y];
  int cnt = segcnt[seg];
  int n0  = blockIdx.x * 256;
  int sb  = segbase[seg];
  const unsigned short* Bw = w1b + (size_t)seg * H * H;
  const float* bias = (seg < 2) ? b1s + (size_t)seg * H : b1r + (size_t)(seg - 2) * H;

  __shared__ __align__(16) unsigned short Al[256 * 64];   // 32 KB
  __shared__ __align__(16) unsigned short Bl[256 * 64];   // 32 KB

  int tid = threadIdx.x;
  int wv = tid >> 6, ln = tid & 63;
  int rw = (wv & 1) * 128, cw = (wv >> 1) * 64;
  int quad = ln >> 4, l16 = ln & 15;
  int lrow = tid >> 3;                          // 0..63 staging row within pass
  int ldst = (tid & 7) * 8;                     // LDS slot (lane*16B contiguous)
  int lkc  = (((tid & 7) ^ (lrow & 7))) * 8;    // swizzled source chunk

  const unsigned short* asrc[4];
  const unsigned short* bsrc[4];
#pragma unroll
  for (int p = 0; p < 4; p++) {
    int row = p * 64 + lrow;                    // row&7 == lrow&7
    int gm  = m0 + row;
    int tok = (gm < cnt) ? rowtok[sb + gm] : 0;
    asrc[p] = xb + (size_t)tok * H + lkc;
    bsrc[p] = Bw + (size_t)(n0 + row) * H + lkc;
  }

  int xsw = (quad ^ (l16 & 7)) * 8;             // swizzled frag read base

  f32x4 acc[8][4];
#pragma unroll
  for (int i = 0; i < 8; i++)
#pragma unroll
    for (int j = 0; j < 4; j++) acc[i][j] = (f32x4){0.f, 0.f, 0.f, 0.f};

  for (int k0 = 0; k0 < H; k0 += 64) {
    __syncthreads();
#pragma unroll
    for (int p = 0; p < 4; p++) {
      int row = p * 64 + lrow;
      gll16(asrc[p] + k0, &Al[row * 64 + ldst]);
      gll16(bsrc[p] + k0, &Bl[row * 64 + ldst]);
    }
    __syncthreads();
#pragma unroll
    for (int kk = 0; kk < 64; kk += 32) {
      bf16x8 af[8], bfr[4];
#pragma unroll
      for (int i = 0; i < 8; i++)
        af[i] = *reinterpret_cast<const bf16x8*>(&Al[(rw + i * 16 + l16) * 64 + (xsw ^ kk)]);
#pragma unroll
      for (int j = 0; j < 4; j++)
        bfr[j] = *reinterpret_cast<const bf16x8*>(&Bl[(cw + j * 16 + l16) * 64 + (xsw ^ kk)]);
#pragma unroll
      for (int i = 0; i < 8; i++)
#pragma unroll
        for (int j = 0; j < 4; j++)
          acc[i][j] = __builtin_amdgcn_mfma_f32_16x16x32_bf16(af[i], bfr[j], acc[i][j], 0, 0, 0);
    }
  }

#pragma unroll
  for (int i = 0; i < 8; i++) {
#pragma unroll
    for (int r = 0; r < 4; r++) {
      int m = m0 + rw + i * 16 + quad * 4 + r;
      if (m >= cnt) continue;
      size_t ro = (size_t)(sb + m) * H;
#pragma unroll
      for (int j = 0; j < 4; j++) {
        int n = n0 + cw + j * 16 + l16;
        float v = acc[i][j][r] + bias[n];
        float g = 0.5f * v * (1.f + erff(v * 0.70710678118654752f));   // exact-erf GELU
        hbuf[ro + n] = f2bf(g);
      }
    }
  }
}

// GEMM2: rbuf[row] = bf16( hbuf[row] @ W2[seg]^T + b2[seg] )
__global__ __launch_bounds__(512, 2) void k_gemm2(
    const unsigned short* __restrict__ hbuf, const unsigned short* __restrict__ w2b,
    const float* __restrict__ b2s, const float* __restrict__ b2r,
    const int* __restrict__ segbase, const int* __restrict__ segcnt,
    const int* __restrict__ tile_seg, const int* __restrict__ tile_m0,
    unsigned short* __restrict__ rbuf) {
  int seg = tile_seg[blockIdx.y];
  if (seg < 0) return;
  int m0  = tile_m0[blockIdx.y];
  int cnt = segcnt[seg];
  int n0  = blockIdx.x * 256;
  int sb  = segbase[seg];
  const unsigned short* Bw = w2b + (size_t)seg * H * H;
  const float* bias = (seg < 2) ? b2s + (size_t)seg * H : b2r + (size_t)(seg - 2) * H;

  __shared__ __align__(16) unsigned short Al[256 * 64];
  __shared__ __align__(16) unsigned short Bl[256 * 64];

  int tid = threadIdx.x;
  int wv = tid >> 6, ln = tid & 63;
  int rw = (wv & 1) * 128, cw = (wv >> 1) * 64;
  int quad = ln >> 4, l16 = ln & 15;
  int lrow = tid >> 3;
  int ldst = (tid & 7) * 8;
  int lkc  = (((tid & 7) ^ (lrow & 7))) * 8;

  const unsigned short* asrc[4];
  const unsigned short* bsrc[4];
#pragma unroll
  for (int p = 0; p < 4; p++) {
    int row = p * 64 + lrow;
    int ar  = sb + m0 + row;
    if (ar >= NROWS) ar = 0;                    // clamp padding rows in-bounds
    asrc[p] = hbuf + (size_t)ar * H + lkc;
    bsrc[p] = Bw + (size_t)(n0 + row) * H + lkc;
  }

  int xsw = (quad ^ (l16 & 7)) * 8;

  f32x4 acc[8][4];
#pragma unroll
  for (int i = 0; i < 8; i++)
#pragma unroll
    for (int j = 0; j < 4; j++) acc[i][j] = (f32x4){0.f, 0.f, 0.f, 0.f};

  for (int k0 = 0; k0 < H; k0 += 64) {
    __syncthreads();
#pragma unroll
    for (int p = 0; p < 4; p++) {
      int row = p * 64 + lrow;
      gll16(asrc[p] + k0, &Al[row * 64 + ldst]);
      gll16(bsrc[p] + k0, &Bl[row * 64 + ldst]);
    }
    __syncthreads();
#pragma unroll
    for (int kk = 0; kk < 64; kk += 32) {
      bf16x8 af[8], bfr[4];
#pragma unroll
      for (int i = 0; i < 8; i++)
        af[i] = *reinterpret_cast<const bf16x8*>(&Al[(rw + i * 16 + l16) * 64 + (xsw ^ kk)]);
#pragma unroll
      for (int j = 0; j < 4; j++)
        bfr[j] = *reinterpret_cast<const bf16x8*>(&Bl[(cw + j * 16 + l16) * 64 + (xsw ^ kk)]);
#pragma unroll
      for (int i = 0; i < 8; i++)
#pragma unroll
        for (int j = 0; j < 4; j++)
          acc[i][j] = __builtin_amdgcn_mfma_f32_16x16x32_bf16(af[i], bfr[j], acc[i][j], 0, 0, 0);
    }
  }

#pragma unroll
  for (int i = 0; i < 8; i++) {
#pragma unroll
    for (int r = 0; r < 4; r++) {
      int m = m0 + rw + i * 16 + quad * 4 + r;
      if (m >= cnt) continue;
      size_t ro = (size_t)(sb + m) * H;
#pragma unroll
      for (int j = 0; j < 4; j++) {
        int n = n0 + cw + j * 16 + l16;
        rbuf[ro + n] = f2bf(acc[i][j][r] + bias[n]);
      }
    }
  }
}

// out[t] = x[t] + rbuf[t] + rbuf[T+t] + sum_j gate_j * rbuf[tokrow[t][j]]
__global__ void k_combine(const float* __restrict__ x, const unsigned short* __restrict__ rbuf,
                          const int* __restrict__ tokrow, const float* __restrict__ topk_g,
                          float* __restrict__ out) {
  int i = blockIdx.x * 256 + threadIdx.x;      // T*H/4 threads
  int t = i / (H / 4);
  int c = (i - t * (H / 4)) * 4;
  size_t xo = (size_t)t * H + c;
  float4 acc = *reinterpret_cast<const float4*>(&x[xo]);
  {
    ushort4 u0 = *reinterpret_cast<const ushort4*>(&rbuf[(size_t)t * H + c]);
    ushort4 u1 = *reinterpret_cast<const ushort4*>(&rbuf[(size_t)(T + t) * H + c]);
    acc.x += bf2f(u0.x) + bf2f(u1.x);
    acc.y += bf2f(u0.y) + bf2f(u1.y);
    acc.z += bf2f(u0.z) + bf2f(u1.z);
    acc.w += bf2f(u0.w) + bf2f(u1.w);
  }
#pragma unroll
  for (int j = 0; j < TK; j++) {
    int r   = tokrow[t * TK + j];
    float g = topk_g[t * TK + j];
    ushort4 u = *reinterpret_cast<const ushort4*>(&rbuf[(size_t)r * H + c]);
    acc.x += g * bf2f(u.x);
    acc.y += g * bf2f(u.y);
    acc.z += g * bf2f(u.z);
    acc.w += g * bf2f(u.w);
  }
  *reinterpret_cast<float4*>(&out[xo]) = acc;
}

// ---------------- host launch ----------------
extern "C" void kernel_launch(void* const* d_in, const int* in_sizes, int n_in,
                              void* d_out, int out_size, void* d_ws, size_t ws_size,
                              hipStream_t stream) {
  const float* x   = (const float*)d_in[0];
  const float* W1s = (const float*)d_in[1];
  const float* b1s = (const float*)d_in[2];
  const float* W2s = (const float*)d_in[3];
  const float* b2s = (const float*)d_in[4];
  const float* W1r = (const float*)d_in[5];
  const float* b1r = (const float*)d_in[6];
  const float* W2r = (const float*)d_in[7];
  const float* b2r = (const float*)d_in[8];
  const float* Wr  = (const float*)d_in[9];
  const float* br  = (const float*)d_in[10];
  float* out = (float*)d_out;

  char* ws = (char*)d_ws;
  const size_t SZ_XB = (size_t)T * H * 2;            // 10.49 MB
  const size_t SZ_WB = (size_t)NE * H * H * 2;       // 52.43 MB each
  const size_t SZ_H  = (size_t)NROWS * H * 2;        // 62.91 MB
  size_t off = 0;
  unsigned short* xb   = (unsigned short*)(ws + off); off += SZ_XB;
  unsigned short* w1b  = (unsigned short*)(ws + off); off += SZ_WB;
  unsigned short* w2b  = (unsigned short*)(ws + off); off += SZ_WB;
  unsigned short* hbuf = (unsigned short*)(ws + off); off += SZ_H;
  int*   rowtok  = (int*)(ws + off);   off += NROWS * 4;
  int*   tokrow  = (int*)(ws + off);   off += T * TK * 4;
  int*   topk_e  = (int*)(ws + off);   off += T * TK * 4;
  float* topk_g  = (float*)(ws + off); off += T * TK * 4;
  int*   cnt     = (int*)(ws + off);   off += 64;
  int*   fill    = (int*)(ws + off);   off += 64;
  int*   segbase = (int*)(ws + off);   off += 64;
  int*   segcnt  = (int*)(ws + off);   off += 64;
  int*   tile_seg = (int*)(ws + off);  off += MAXT * 4;
  int*   tile_m0  = (int*)(ws + off);  off += MAXT * 4;
  // rbuf aliases [xb][w1b] (exactly NROWS*H*2 bytes) — both dead once gemm2 runs.
  unsigned short* rbuf = (unsigned short*)ws;

  hipLaunchKernelGGL(k_init, dim3(1), dim3(64), 0, stream, cnt, fill);
  hipLaunchKernelGGL(k_cast_x, dim3((T * H / 4) / 256), dim3(256), 0, stream, x, xb);
  hipLaunchKernelGGL(k_transpose, dim3(20, 20, 32), dim3(256), 0, stream,
                     W1s, W2s, W1r, W2r, w1b, w2b);
  hipLaunchKernelGGL(k_router, dim3(T / 4), dim3(256), 0, stream, x, Wr, br, topk_e, topk_g);
  hipLaunchKernelGGL(k_count, dim3(T / 256), dim3(256), 0, stream, topk_e, cnt);
  hipLaunchKernelGGL(k_prefix, dim3(1), dim3(1), 0, stream, cnt, segbase, segcnt, tile_seg, tile_m0);
  hipLaunchKernelGGL(k_fill, dim3(T / 256), dim3(256), 0, stream,
                     topk_e, segbase, fill, rowtok, tokrow);
  hipLaunchKernelGGL(k_gemm1, dim3(5, MAXT, 1), dim3(512), 0, stream,
                     xb, w1b, b1s, b1r, rowtok, segbase, segcnt, tile_seg, tile_m0, hbuf);
  hipLaunchKernelGGL(k_gemm2, dim3(5, MAXT, 1), dim3(512), 0, stream,
                     hbuf, w2b, b2s, b2r, segbase, segcnt, tile_seg, tile_m0, rbuf);
  hipLaunchKernelGGL(k_combine, dim3((T * H / 4) / 256), dim3(256), 0, stream,
                     x, rbuf, tokrow, topk_g, out);
}